// Round 6
// baseline (663.359 us; speedup 1.0000x reference)
//
#include <hip/hip_runtime.h>

// T2ICrossAttentionPool on MI355X.
// Identities: w12[c,i,w] = sum_r attn*Sraw;  |wctx|^2 = a^T G a with
//   G = exact fp32 diag (register math) + off-diag G' bf16 (MFMA quadratic form).
// R13: transposed epilogue, reg K-loop, (256,3): 433us (MFMA floor 124us).
// R14/R15: LDS-staged K-loop @ (256,4) spilled BOTH times: (256,4) caps the
//   unified file at 128/thread; allocator split 64 arch + 64 acc -> ~45 regs
//   of epilogue state to scratch (WRITE_SIZE 379-395MB, HBM 1.6TB/s).
// R16: SAME staged kernel at (256,3) (cap ~170: ~104 arch + 64 acc, the
//   proven-clean R13 allocation). Equal occupancy to R13 -> clean A/B of
//   staging (TA traffic halved, frags via LDS pipe) vs register K-loop.

#define NIMG 256
#define NREG 36
#define DIM 1024
#define NCAP 256
#define MAXW 60
#define WPAD 64

typedef short bf16x8 __attribute__((ext_vector_type(8)));
typedef float f32x4 __attribute__((ext_vector_type(4)));

__device__ __forceinline__ unsigned short f2bf(float f) {
  unsigned u = __float_as_uint(f);
  u += 0x7FFF + ((u >> 16) & 1);   // round-to-nearest-even
  return (unsigned short)(u >> 16);
}

// async global->LDS, 16B per lane; LDS dest = uniform base + lane*16
__device__ __forceinline__ void gll16(const unsigned short* g, unsigned short* l) {
  __builtin_amdgcn_global_load_lds((const __attribute__((address_space(1))) void*)g,
                                   (__attribute__((address_space(3))) void*)l, 16, 0, 0);
}

// ---- prep: w1[c][w] = ||masked q row|| ----
__global__ void k_prep_w1(const float* __restrict__ caps, const int* __restrict__ cap_lens,
                          float* __restrict__ w1) {
  const int bid = blockIdx.x;          // c*64 + w
  const int c = bid >> 6;
  const int w = bid & 63;
  const int t = threadIdx.x;
  const bool valid = (w < MAXW) && (w < cap_lens[c]);
  float4 v = make_float4(0.f, 0.f, 0.f, 0.f);
  if (valid) v = *reinterpret_cast<const float4*>(caps + ((size_t)c * MAXW + w) * DIM + t * 4);
  float ss = v.x * v.x + v.y * v.y + v.z * v.z + v.w * v.w;
#pragma unroll
  for (int m = 1; m <= 32; m <<= 1) ss += __shfl_xor(ss, m);
  __shared__ float part[4];
  if ((t & 63) == 0) part[t >> 6] = ss;
  __syncthreads();
  if (t == 0) w1[bid] = sqrtf(part[0] + part[1] + part[2] + part[3]);
}

// ---- prep: caption permutation sorted by length (rank-count, 1 block) ----
__global__ void k_sort(const int* __restrict__ cap_lens, int* __restrict__ perm) {
  const int i = threadIdx.x;           // 256 threads
  const int li = cap_lens[i];
  int r = 0;
  for (int j = 0; j < NCAP; ++j) {
    const int lj = cap_lens[j];
    r += (lj < li) || (lj == li && j < i);
  }
  perm[r] = i;
}

// ---- prep: caps -> fragments, masked (rows w>=clen zero) ----
// Layout: qbfF[(((c*32 + k32)*4 + mt)*64 + lane)*8 + j]
//   = q[c][m = mt*16 + (lane&15)][k = k32*32 + (lane>>4)*8 + j]
__global__ void k_prep_caps_frag(const float* __restrict__ caps, const int* __restrict__ cap_lens,
                                 unsigned short* __restrict__ qbfF) {
  const int k32 = blockIdx.x;
  const int c = blockIdx.y;
  const int t = threadIdx.x;
  const int mt = t >> 6;
  const int lane = t & 63;
  const int m = mt * 16 + (lane & 15);
  const int k0 = k32 * 32 + (lane >> 4) * 8;
  const int clen = cap_lens[c];
  float4 v0 = make_float4(0.f, 0.f, 0.f, 0.f), v1 = v0;
  if (m < clen && m < MAXW) {
    const float* src = caps + ((size_t)c * MAXW + m) * DIM + k0;
    v0 = *reinterpret_cast<const float4*>(src);
    v1 = *reinterpret_cast<const float4*>(src + 4);
  }
  ushort4 o0, o1;
  o0.x = f2bf(v0.x); o0.y = f2bf(v0.y); o0.z = f2bf(v0.z); o0.w = f2bf(v0.w);
  o1.x = f2bf(v1.x); o1.y = f2bf(v1.y); o1.z = f2bf(v1.z); o1.w = f2bf(v1.w);
  unsigned short* dst = qbfF + ((size_t)(((c * 32 + k32) * 4 + mt) * 64 + lane)) * 8;
  *reinterpret_cast<ushort4*>(dst) = o0;
  *reinterpret_cast<ushort4*>(dst + 4) = o1;
}

// ---- prep: imgs -> fragments (rows r>=36 zero) ----
// Layout: ibfF[(((i*32 + k32)*3 + nt)*64 + lane)*8 + j]
//   = imgs[i][r = nt*16 + (lane&15)][k = k32*32 + (lane>>4)*8 + j]
__global__ void k_prep_imgs_frag(const float* __restrict__ imgs,
                                 unsigned short* __restrict__ ibfF) {
  const int k32 = blockIdx.x;
  const int i = blockIdx.y;
  const int t = threadIdx.x;          // 0..191
  const int nt = t >> 6;
  const int lane = t & 63;
  const int r = nt * 16 + (lane & 15);
  const int k0 = k32 * 32 + (lane >> 4) * 8;
  float4 v0 = make_float4(0.f, 0.f, 0.f, 0.f), v1 = v0;
  if (r < NREG) {
    const float* src = imgs + ((size_t)i * NREG + r) * DIM + k0;
    v0 = *reinterpret_cast<const float4*>(src);
    v1 = *reinterpret_cast<const float4*>(src + 4);
  }
  ushort4 o0, o1;
  o0.x = f2bf(v0.x); o0.y = f2bf(v0.y); o0.z = f2bf(v0.z); o0.w = f2bf(v0.w);
  o1.x = f2bf(v1.x); o1.y = f2bf(v1.y); o1.z = f2bf(v1.z); o1.w = f2bf(v1.w);
  unsigned short* dst = ibfF + ((size_t)(((i * 32 + k32) * 3 + nt) * 64 + lane)) * 8;
  *reinterpret_cast<ushort4*>(dst) = o0;
  *reinterpret_cast<ushort4*>(dst + 4) = o1;
}

// ---- Gram via MFMA: one wave per image (same ibfF line feeds both operands) ----
__global__ void k_gram_mfma(const float* __restrict__ imgs,
                            const unsigned short* __restrict__ ibfF,
                            unsigned short* __restrict__ gbf,
                            float* __restrict__ gdiag) {
  const int i = blockIdx.x;
  const int lane = threadIdx.x & 63;
  const int l15 = lane & 15;
  const int quad = lane >> 4;

  // exact fp32 diag: rows r0+quad, k split across the 16 lanes of each quad
  float* dg = gdiag + (size_t)i * 48;
#pragma unroll
  for (int r0 = 0; r0 < 36; r0 += 4) {
    const int r = r0 + quad;
    const float* row = imgs + ((size_t)i * NREG + r) * DIM;
    float ss = 0.f;
#pragma unroll
    for (int p = 0; p < 16; ++p) {
      float4 v = *reinterpret_cast<const float4*>(row + p * 64 + l15 * 4);
      ss += v.x * v.x + v.y * v.y + v.z * v.z + v.w * v.w;
    }
    ss += __shfl_xor(ss, 1); ss += __shfl_xor(ss, 2);
    ss += __shfl_xor(ss, 4); ss += __shfl_xor(ss, 8);
    if (l15 == 0) dg[r] = ss;
  }
  if (lane < 12) dg[36 + lane] = 0.f;

  const unsigned short* base = ibfF + ((size_t)i * 32 * 3) * 512 + lane * 8;
  const f32x4 zero4 = {0.f, 0.f, 0.f, 0.f};
  f32x4 acc[3][3];
#pragma unroll
  for (int na = 0; na < 3; ++na)
#pragma unroll
    for (int nb = 0; nb < 3; ++nb) acc[na][nb] = zero4;
  bf16x8 f[2][3];
#pragma unroll
  for (int nt = 0; nt < 3; ++nt)
    f[0][nt] = *reinterpret_cast<const bf16x8*>(base + (size_t)nt * 512);
#pragma unroll
  for (int k32 = 0; k32 < 32; ++k32) {
    if (k32 + 1 < 32) {
      const int nb_ = (k32 + 1) & 1;
#pragma unroll
      for (int nt = 0; nt < 3; ++nt)
        f[nb_][nt] = *reinterpret_cast<const bf16x8*>(base + ((size_t)(k32 + 1) * 3 + nt) * 512);
    }
    const int b = k32 & 1;
#pragma unroll
    for (int na = 0; na < 3; ++na)
#pragma unroll
      for (int nb = 0; nb < 3; ++nb)
        acc[na][nb] = __builtin_amdgcn_mfma_f32_16x16x32_bf16(f[b][na], f[b][nb], acc[na][nb], 0, 0, 0);
  }
  unsigned short* g = gbf + (size_t)i * (48 * 64);
#pragma unroll
  for (int na = 0; na < 3; ++na)
#pragma unroll
    for (int nb = 0; nb < 3; ++nb)
#pragma unroll
      for (int rg = 0; rg < 4; ++rg) {
        const int r = na * 16 + quad * 4 + rg;   // C row
        const int c = nb * 16 + l15;             // C col
        g[r * 64 + c] = (r == c) ? (unsigned short)0 : f2bf(acc[na][nb][rg]);
      }
  // zero the K-pad cols 48..63 (16 ushorts = 2 uint4 per row)
  for (int idx = lane; idx < 96; idx += 64) {
    const int r = idx >> 1, half = idx & 1;
    *reinterpret_cast<uint4*>(g + r * 64 + 48 + half * 8) = make_uint4(0, 0, 0, 0);
  }
}

// ---- K-loop: LDS-staged, double-buffered, 1 barrier per k32 ----
#define BUFO 7168   // ushorts per stage buffer
template <int MLIM>
__device__ __forceinline__ void kloopS(const unsigned short* __restrict__ sSrc,
                                       unsigned short* __restrict__ sDst,
                                       const int sCnt, const size_t sK32,
                                       const unsigned short* __restrict__ aLds,
                                       const unsigned short* __restrict__ bLds,
                                       f32x4 (&acc)[3][4]) {
  // prologue: stage k32=0 into buf 0
  for (int j = 0; j < sCnt; ++j)
    gll16(sSrc + j * 512, sDst + j * 512);
  __syncthreads();
#pragma unroll 2
  for (int t = 0; t < 32; ++t) {
    const int cur = t & 1;
    if (t + 1 < 32) {
      unsigned short* d = sDst + (cur ^ 1) * BUFO;
      const unsigned short* s = sSrc + (size_t)(t + 1) * sK32;
      for (int j = 0; j < sCnt; ++j)
        gll16(s + j * 512, d + j * 512);
    }
    bf16x8 fb[3], fa[MLIM];
#pragma unroll
    for (int nt = 0; nt < 3; ++nt)
      fb[nt] = *reinterpret_cast<const bf16x8*>(bLds + cur * BUFO + nt * 512);
#pragma unroll
    for (int mt = 0; mt < MLIM; ++mt)
      fa[mt] = *reinterpret_cast<const bf16x8*>(aLds + cur * BUFO + mt * 512);
#pragma unroll
    for (int mt = 0; mt < MLIM; ++mt)
#pragma unroll
      for (int nt = 0; nt < 3; ++nt)
        acc[nt][mt] = __builtin_amdgcn_mfma_f32_16x16x32_bf16(fb[nt], fa[mt], acc[nt][mt], 0, 0, 0);
    __syncthreads();
  }
}

// ---- main fused kernel ----
// Grid (I/2, C/2), block 256 = 4 waves: wave wv -> (cap wv&1 of sorted pair,
// img i0+(wv>>1)). XCD swizzle: each XCD owns a 16-wide image-pair stripe.
__launch_bounds__(256, 3)
__global__ void k_main(const unsigned short* __restrict__ qbfF,
                       const unsigned short* __restrict__ ibfF,
                       const float* __restrict__ w1,
                       const unsigned short* __restrict__ gbf,
                       const float* __restrict__ gdiag,
                       const int* __restrict__ cap_lens,
                       const int* __restrict__ perm,
                       float* __restrict__ out) {
  __shared__ union {
    unsigned short stg[2][BUFO];      // [dbuf][capA 4t | capB 4t | img0 3t | img1 3t] = 28672 B
    unsigned short attn[4][4096];     // post-loop: bf16 [w][r] per wave, 32768 B
  } u;
  __shared__ float w12s[4][64], w2ds[4][64], w2xs[4][64];   // 3072 B -> total 35840
  const int tid = threadIdx.x;
  const int lane = tid & 63;
  const int wv = tid >> 6;
  const int l15 = lane & 15;
  const int quad = lane >> 4;
  // ---- XCD-aware swizzle (16384 blocks, %8==0 -> bijective) ----
  const int flat = blockIdx.y * (NIMG / 2) + blockIdx.x;
  const int xcd = flat & 7;
  const int idx = flat >> 3;
  const int bx = xcd * 16 + (idx & 15);
  const int by = idx >> 4;
  const int i0 = bx * 2;
  const int cA = perm[2 * by], cB = perm[2 * by + 1];
  const int c = (wv & 1) ? cB : cA;
  const int img = i0 + (wv >> 1);
  const int clen = cap_lens[c];
  const int mlim = (clen + 15) >> 4;   // 1..4 valid w-tiles (this wave)

  // stage role: wv0->capA frags, wv1->capB, wv2->img0, wv3->img1
  const unsigned short* sSrc;
  unsigned short* sDst;
  int sCnt;
  size_t sK32;
  if (wv == 0) {
    sSrc = qbfF + (size_t)cA * 32 * 4 * 512; sDst = &u.stg[0][0];
    sCnt = (cap_lens[cA] + 15) >> 4; sK32 = 4 * 512;
  } else if (wv == 1) {
    sSrc = qbfF + (size_t)cB * 32 * 4 * 512; sDst = &u.stg[0][2048];
    sCnt = (cap_lens[cB] + 15) >> 4; sK32 = 4 * 512;
  } else if (wv == 2) {
    sSrc = ibfF + (size_t)i0 * 32 * 3 * 512; sDst = &u.stg[0][4096];
    sCnt = 3; sK32 = 3 * 512;
  } else {
    sSrc = ibfF + (size_t)(i0 + 1) * 32 * 3 * 512; sDst = &u.stg[0][5632];
    sCnt = 3; sK32 = 3 * 512;
  }
  sSrc += lane * 8;
  const unsigned short* aLds = &u.stg[0][(wv & 1) * 2048] + lane * 8;
  const unsigned short* bLds = &u.stg[0][4096 + (wv >> 1) * 1536] + lane * 8;

  f32x4 acc[3][4];
  const f32x4 zero4 = {0.f, 0.f, 0.f, 0.f};
#pragma unroll
  for (int nt = 0; nt < 3; ++nt)
#pragma unroll
    for (int mt = 0; mt < 4; ++mt) acc[nt][mt] = zero4;

  switch (mlim) {
    case 1: kloopS<1>(sSrc, sDst, sCnt, sK32, aLds, bLds, acc); break;
    case 2: kloopS<2>(sSrc, sDst, sCnt, sK32, aLds, bLds, acc); break;
    case 3: kloopS<3>(sSrc, sDst, sCnt, sK32, aLds, bLds, acc); break;
    default: kloopS<4>(sSrc, sDst, sCnt, sK32, aLds, bLds, acc); break;
  }
  // last loop iteration ended with __syncthreads(): stage buffers dead, union
  // safe to reuse as attn region (wave-private slices from here on).

  {
    uint4* ab = reinterpret_cast<uint4*>(&u.attn[wv][0]);
    const uint4 z4 = make_uint4(0, 0, 0, 0);
    for (int j = lane; j < 512; j += 64) ab[j] = z4;   // zero all (incl. pad groups)
  }

  // exact diag per register row r = nt*16 + quad*4 + rg
  const float* dg = gdiag + (size_t)img * 48;
  float dv[3][4];
#pragma unroll
  for (int nt = 0; nt < 3; ++nt)
#pragma unroll
    for (int rg = 0; rg < 4; ++rg)
      dv[nt][rg] = dg[nt * 16 + quad * 4 + rg];

  // pass 1: per-region l2 norm over w -> scale (w = lane dim: in-reg over mt,
  // then xor1..8; 12 independent butterflies, ILP-overlapped)
  float scale[3][4];
#pragma unroll
  for (int nt = 0; nt < 3; ++nt)
#pragma unroll
    for (int rg = 0; rg < 4; ++rg) {
      float p = 0.f;
#pragma unroll
      for (int mt = 0; mt < 4; ++mt)
        if (mt < mlim) {
          const float s = acc[nt][mt][rg];
          const float l = s < 0.f ? 0.1f * s : s;
          p += l * l;
        }
      p += __shfl_xor(p, 1); p += __shfl_xor(p, 2);
      p += __shfl_xor(p, 4); p += __shfl_xor(p, 8);
      scale[nt][rg] = 9.0f / (sqrtf(p) + 1e-8f);   // SMOOTH folded in
    }

  // pass 2: softmax over r per w-column. |t| <= 9 -> no max subtraction.
  // Invalid r (>=36): nt==2 && quad!=0 -> e=0. Normalized attn packed as bf16
  // pairs in 24 u32 regs (bit-identical to the LDS attn values).
  unsigned a_pk[4][3][2];
#pragma unroll
  for (int mt = 0; mt < 4; ++mt) {
    if (mt >= mlim) continue;
    float ee[3][4];
    float sm = 0.f, wp = 0.f, dd = 0.f;
#pragma unroll
    for (int nt = 0; nt < 3; ++nt) {
      const bool rvalid = (nt < 2) || (quad == 0);
#pragma unroll
      for (int rg = 0; rg < 4; ++rg) {
        const float s = acc[nt][mt][rg];
        const float l = s < 0.f ? 0.1f * s : s;
        const float e0 = rvalid ? __expf(l * scale[nt][rg]) : 0.f;
        ee[nt][rg] = e0;
        sm += e0;
        wp += e0 * s;                       // w12 uses RAW s
        dd += e0 * e0 * dv[nt][rg];         // exact diag term
      }
    }
    sm += __shfl_xor(sm, 16); sm += __shfl_xor(sm, 32);
    wp += __shfl_xor(wp, 16); wp += __shfl_xor(wp, 32);
    dd += __shfl_xor(dd, 16); dd += __shfl_xor(dd, 32);
    const float inv = 1.0f / sm;
    const int w = mt * 16 + l15;
    const int key = l15 & 7;
    unsigned short* arow = &u.attn[wv][w * 64];
#pragma unroll
    for (int nt = 0; nt < 3; ++nt)
#pragma unroll
      for (int pr = 0; pr < 2; ++pr) {
        const unsigned b0 = f2bf(ee[nt][2 * pr] * inv);
        const unsigned b1 = f2bf(ee[nt][2 * pr + 1] * inv);
        const unsigned pk = b0 | (b1 << 16);
        a_pk[mt][nt][pr] = pk;
        // r0 = nt*16+quad*4+2pr (even), r1 = r0+1: same 8-group, adjacent ->
        // one aligned u32 LDS store.
        const int r0 = nt * 16 + quad * 4 + 2 * pr;
        *reinterpret_cast<unsigned*>(&arow[(((r0 >> 3) ^ key) << 3) + (r0 & 7)]) = pk;
      }
    if (quad == 0) { w12s[wv][w] = wp * inv; w2ds[wv][w] = dd * inv * inv; }
  }

  // Yt = G x Attn^T via MFMA (A=G rows r, B=attn cols w) -> Yt[nt][rg] at lane
  // (l15,quad) = Y[r = nt*16+quad*4+rg][w = mt*16+l15]: SAME layout as a_pk.
  bf16x8 gfrag[3][2];
#pragma unroll
  for (int nt = 0; nt < 3; ++nt)
#pragma unroll
    for (int ks = 0; ks < 2; ++ks)
      gfrag[nt][ks] = *reinterpret_cast<const bf16x8*>(
          gbf + ((size_t)img * 48 + nt * 16 + l15) * 64 + ((ks * 4 + quad) << 3));
#pragma unroll
  for (int mt = 0; mt < 4; ++mt) {
    if (mt >= mlim) continue;
    bf16x8 af[2];
#pragma unroll
    for (int ks = 0; ks < 2; ++ks)
      af[ks] = *reinterpret_cast<const bf16x8*>(
          &u.attn[wv][(mt * 16 + l15) * 64 + (((ks * 4 + quad) ^ (l15 & 7)) << 3)]);
    f32x4 Yt[3] = {zero4, zero4, zero4};
#pragma unroll
    for (int nt = 0; nt < 3; ++nt)
#pragma unroll
      for (int ks = 0; ks < 2; ++ks)
        Yt[nt] = __builtin_amdgcn_mfma_f32_16x16x32_bf16(gfrag[nt][ks], af[ks], Yt[nt], 0, 0, 0);
    // cross term: w2x[w] = sum_r a[w][r] * Y[r][w]; a unpacked from bf16 pairs
    float p = 0.f;
#pragma unroll
    for (int nt = 0; nt < 3; ++nt)
#pragma unroll
      for (int pr = 0; pr < 2; ++pr) {
        const unsigned pk = a_pk[mt][nt][pr];
        const float a0 = __uint_as_float(pk << 16);
        const float a1 = __uint_as_float(pk & 0xffff0000u);
        p += a0 * Yt[nt][2 * pr] + a1 * Yt[nt][2 * pr + 1];
      }
    p += __shfl_xor(p, 16); p += __shfl_xor(p, 32);
    if (quad == 0) w2xs[wv][mt * 16 + l15] = p;
  }

  // final: lane = word
  float simv = 0.f;
  if (lane < clen) {
    const float w2sq = fmaxf(w2xs[wv][lane] + w2ds[wv][lane], 0.f);
    const float w2v = sqrtf(w2sq);
    const float w12v = w12s[wv][lane];
    const float w1v = w1[(size_t)c * WPAD + lane];
    simv = w12v / fmaxf(w1v * w2v, 1e-8f);
  }
  simv += __shfl_xor(simv, 1);
  simv += __shfl_xor(simv, 2);
  simv += __shfl_xor(simv, 4);
  simv += __shfl_xor(simv, 8);
  simv += __shfl_xor(simv, 16);
  simv += __shfl_xor(simv, 32);
  if (lane == 0) out[(size_t)img * NCAP + c] = simv / (float)clen;
}

extern "C" void kernel_launch(void* const* d_in, const int* in_sizes, int n_in,
                              void* d_out, int out_size, void* d_ws, size_t ws_size,
                              hipStream_t stream) {
  const float* imgs = (const float*)d_in[0];
  const float* caps = (const float*)d_in[1];
  const int* cap_lens = (const int*)d_in[3];   // img_lens (d_in[2]) unused by reference
  float* out = (float*)d_out;

  char* ws = (char*)d_ws;
  const size_t QBF_B = (size_t)NCAP * 32 * 4 * 512 * 2;      // 33,554,432
  const size_t IBF_B = (size_t)NIMG * 32 * 3 * 512 * 2;      // 25,165,824
  const size_t W1_B = (size_t)NCAP * WPAD * 4;               // 65,536
  const size_t GBF_B = (size_t)NIMG * 48 * 64 * 2;           // 1,572,864
  const size_t GD_B = (size_t)NIMG * 48 * 4;                 // 49,152
  unsigned short* qbfF = (unsigned short*)ws;
  unsigned short* ibfF = (unsigned short*)(ws + QBF_B);
  float* w1 = (float*)(ws + QBF_B + IBF_B);
  unsigned short* gbf = (unsigned short*)(ws + QBF_B + IBF_B + W1_B);
  float* gdiag = (float*)(ws + QBF_B + IBF_B + W1_B + GBF_B);
  int* perm = (int*)(ws + QBF_B + IBF_B + W1_B + GBF_B + GD_B);

  k_prep_w1<<<NCAP * WPAD, 256, 0, stream>>>(caps, cap_lens, w1);
  k_sort<<<1, NCAP, 0, stream>>>(cap_lens, perm);
  k_prep_caps_frag<<<dim3(32, NCAP), 256, 0, stream>>>(caps, cap_lens, qbfF);
  k_prep_imgs_frag<<<dim3(32, NIMG), 192, 0, stream>>>(imgs, ibfF);
  k_gram_mfma<<<NIMG, 64, 0, stream>>>(imgs, ibfF, gbf, gdiag);
  k_main<<<dim3(NIMG / 2, NCAP / 2), 256, 0, stream>>>(qbfF, ibfF, w1, gbf, gdiag, cap_lens, perm, out);
}

// Round 8
// 551.481 us; speedup vs baseline: 1.2029x; 1.2029x over previous
//
#include <hip/hip_runtime.h>

// T2ICrossAttentionPool on MI355X.
// Identities: w12[c,i,w] = sum_r attn*Sraw;  |wctx|^2 = a^T G a with
//   G = exact fp32 diag (register math) + off-diag G' bf16 (MFMA quadratic form).
// R13: transposed epilogue, reg K-loop, (256,3): 433us (MFMA floor 124us).
// R16: staged loop, __syncthreads/iter: 557us (vmcnt(0) drain ~300cy/iter).
// R17: counted vmcnt + ONE raw barrier/iter: RACED (absmax 4.9e-4 -> 2e-3,
//   run-to-run divergence). Missing invariant: no "all reads done" barrier
//   before overwriting the buffer (MFMAs sink past asm waits, rule #18).
// R18: m201's TWO-barrier schedule, 2 buffers, zero main-loop drains:
//   vmcnt(SCNT) -> bar1 (stage(t) landed) -> ds_read + lgkmcnt(0) + schedbar
//   -> bar2 (all reads done) -> stage(t+2, same buf) -> MFMA. Tail peeled
//   (t=30: vmcnt(SCNT), t=31: vmcnt(0)); 62 barriers/wave uniform.

#define NIMG 256
#define NREG 36
#define DIM 1024
#define NCAP 256
#define MAXW 60
#define WPAD 64

typedef short bf16x8 __attribute__((ext_vector_type(8)));
typedef float f32x4 __attribute__((ext_vector_type(4)));

__device__ __forceinline__ unsigned short f2bf(float f) {
  unsigned u = __float_as_uint(f);
  u += 0x7FFF + ((u >> 16) & 1);   // round-to-nearest-even
  return (unsigned short)(u >> 16);
}

// async global->LDS, 16B per lane; LDS dest = wave-uniform base + lane*16
__device__ __forceinline__ void gll16(const unsigned short* g, unsigned short* l) {
  __builtin_amdgcn_global_load_lds((const __attribute__((address_space(1))) void*)g,
                                   (__attribute__((address_space(3))) void*)l, 16, 0, 0);
}

template <int N>
__device__ __forceinline__ void waitcnt_vm() {
  if constexpr (N == 0) asm volatile("s_waitcnt vmcnt(0)" ::: "memory");
  else if constexpr (N == 1) asm volatile("s_waitcnt vmcnt(1)" ::: "memory");
  else if constexpr (N == 2) asm volatile("s_waitcnt vmcnt(2)" ::: "memory");
  else if constexpr (N == 3) asm volatile("s_waitcnt vmcnt(3)" ::: "memory");
  else asm volatile("s_waitcnt vmcnt(4)" ::: "memory");
}

// ---- prep: w1[c][w] = ||masked q row|| ----
__global__ void k_prep_w1(const float* __restrict__ caps, const int* __restrict__ cap_lens,
                          float* __restrict__ w1) {
  const int bid = blockIdx.x;          // c*64 + w
  const int c = bid >> 6;
  const int w = bid & 63;
  const int t = threadIdx.x;
  const bool valid = (w < MAXW) && (w < cap_lens[c]);
  float4 v = make_float4(0.f, 0.f, 0.f, 0.f);
  if (valid) v = *reinterpret_cast<const float4*>(caps + ((size_t)c * MAXW + w) * DIM + t * 4);
  float ss = v.x * v.x + v.y * v.y + v.z * v.z + v.w * v.w;
#pragma unroll
  for (int m = 1; m <= 32; m <<= 1) ss += __shfl_xor(ss, m);
  __shared__ float part[4];
  if ((t & 63) == 0) part[t >> 6] = ss;
  __syncthreads();
  if (t == 0) w1[bid] = sqrtf(part[0] + part[1] + part[2] + part[3]);
}

// ---- prep: caption permutation sorted by length (rank-count, 1 block) ----
__global__ void k_sort(const int* __restrict__ cap_lens, int* __restrict__ perm) {
  const int i = threadIdx.x;           // 256 threads
  const int li = cap_lens[i];
  int r = 0;
  for (int j = 0; j < NCAP; ++j) {
    const int lj = cap_lens[j];
    r += (lj < li) || (lj == li && j < i);
  }
  perm[r] = i;
}

// ---- prep: caps -> fragments, masked (rows w>=clen zero) ----
// Layout: qbfF[(((c*32 + k32)*4 + mt)*64 + lane)*8 + j]
//   = q[c][m = mt*16 + (lane&15)][k = k32*32 + (lane>>4)*8 + j]
__global__ void k_prep_caps_frag(const float* __restrict__ caps, const int* __restrict__ cap_lens,
                                 unsigned short* __restrict__ qbfF) {
  const int k32 = blockIdx.x;
  const int c = blockIdx.y;
  const int t = threadIdx.x;
  const int mt = t >> 6;
  const int lane = t & 63;
  const int m = mt * 16 + (lane & 15);
  const int k0 = k32 * 32 + (lane >> 4) * 8;
  const int clen = cap_lens[c];
  float4 v0 = make_float4(0.f, 0.f, 0.f, 0.f), v1 = v0;
  if (m < clen && m < MAXW) {
    const float* src = caps + ((size_t)c * MAXW + m) * DIM + k0;
    v0 = *reinterpret_cast<const float4*>(src);
    v1 = *reinterpret_cast<const float4*>(src + 4);
  }
  ushort4 o0, o1;
  o0.x = f2bf(v0.x); o0.y = f2bf(v0.y); o0.z = f2bf(v0.z); o0.w = f2bf(v0.w);
  o1.x = f2bf(v1.x); o1.y = f2bf(v1.y); o1.z = f2bf(v1.z); o1.w = f2bf(v1.w);
  unsigned short* dst = qbfF + ((size_t)(((c * 32 + k32) * 4 + mt) * 64 + lane)) * 8;
  *reinterpret_cast<ushort4*>(dst) = o0;
  *reinterpret_cast<ushort4*>(dst + 4) = o1;
}

// ---- prep: imgs -> fragments (rows r>=36 zero) ----
// Layout: ibfF[(((i*32 + k32)*3 + nt)*64 + lane)*8 + j]
//   = imgs[i][r = nt*16 + (lane&15)][k = k32*32 + (lane>>4)*8 + j]
__global__ void k_prep_imgs_frag(const float* __restrict__ imgs,
                                 unsigned short* __restrict__ ibfF) {
  const int k32 = blockIdx.x;
  const int i = blockIdx.y;
  const int t = threadIdx.x;          // 0..191
  const int nt = t >> 6;
  const int lane = t & 63;
  const int r = nt * 16 + (lane & 15);
  const int k0 = k32 * 32 + (lane >> 4) * 8;
  float4 v0 = make_float4(0.f, 0.f, 0.f, 0.f), v1 = v0;
  if (r < NREG) {
    const float* src = imgs + ((size_t)i * NREG + r) * DIM + k0;
    v0 = *reinterpret_cast<const float4*>(src);
    v1 = *reinterpret_cast<const float4*>(src + 4);
  }
  ushort4 o0, o1;
  o0.x = f2bf(v0.x); o0.y = f2bf(v0.y); o0.z = f2bf(v0.z); o0.w = f2bf(v0.w);
  o1.x = f2bf(v1.x); o1.y = f2bf(v1.y); o1.z = f2bf(v1.z); o1.w = f2bf(v1.w);
  unsigned short* dst = ibfF + ((size_t)(((i * 32 + k32) * 3 + nt) * 64 + lane)) * 8;
  *reinterpret_cast<ushort4*>(dst) = o0;
  *reinterpret_cast<ushort4*>(dst + 4) = o1;
}

// ---- Gram via MFMA: one wave per image (same ibfF line feeds both operands) ----
__global__ void k_gram_mfma(const float* __restrict__ imgs,
                            const unsigned short* __restrict__ ibfF,
                            unsigned short* __restrict__ gbf,
                            float* __restrict__ gdiag) {
  const int i = blockIdx.x;
  const int lane = threadIdx.x & 63;
  const int l15 = lane & 15;
  const int quad = lane >> 4;

  // exact fp32 diag: rows r0+quad, k split across the 16 lanes of each quad
  float* dg = gdiag + (size_t)i * 48;
#pragma unroll
  for (int r0 = 0; r0 < 36; r0 += 4) {
    const int r = r0 + quad;
    const float* row = imgs + ((size_t)i * NREG + r) * DIM;
    float ss = 0.f;
#pragma unroll
    for (int p = 0; p < 16; ++p) {
      float4 v = *reinterpret_cast<const float4*>(row + p * 64 + l15 * 4);
      ss += v.x * v.x + v.y * v.y + v.z * v.z + v.w * v.w;
    }
    ss += __shfl_xor(ss, 1); ss += __shfl_xor(ss, 2);
    ss += __shfl_xor(ss, 4); ss += __shfl_xor(ss, 8);
    if (l15 == 0) dg[r] = ss;
  }
  if (lane < 12) dg[36 + lane] = 0.f;

  const unsigned short* base = ibfF + ((size_t)i * 32 * 3) * 512 + lane * 8;
  const f32x4 zero4 = {0.f, 0.f, 0.f, 0.f};
  f32x4 acc[3][3];
#pragma unroll
  for (int na = 0; na < 3; ++na)
#pragma unroll
    for (int nb = 0; nb < 3; ++nb) acc[na][nb] = zero4;
  bf16x8 f[2][3];
#pragma unroll
  for (int nt = 0; nt < 3; ++nt)
    f[0][nt] = *reinterpret_cast<const bf16x8*>(base + (size_t)nt * 512);
#pragma unroll
  for (int k32 = 0; k32 < 32; ++k32) {
    if (k32 + 1 < 32) {
      const int nb_ = (k32 + 1) & 1;
#pragma unroll
      for (int nt = 0; nt < 3; ++nt)
        f[nb_][nt] = *reinterpret_cast<const bf16x8*>(base + ((size_t)(k32 + 1) * 3 + nt) * 512);
    }
    const int b = k32 & 1;
#pragma unroll
    for (int na = 0; na < 3; ++na)
#pragma unroll
      for (int nb = 0; nb < 3; ++nb)
        acc[na][nb] = __builtin_amdgcn_mfma_f32_16x16x32_bf16(f[b][na], f[b][nb], acc[na][nb], 0, 0, 0);
  }
  unsigned short* g = gbf + (size_t)i * (48 * 64);
#pragma unroll
  for (int na = 0; na < 3; ++na)
#pragma unroll
    for (int nb = 0; nb < 3; ++nb)
#pragma unroll
      for (int rg = 0; rg < 4; ++rg) {
        const int r = na * 16 + quad * 4 + rg;   // C row
        const int c = nb * 16 + l15;             // C col
        g[r * 64 + c] = (r == c) ? (unsigned short)0 : f2bf(acc[na][nb][rg]);
      }
  // zero the K-pad cols 48..63 (16 ushorts = 2 uint4 per row)
  for (int idx = lane; idx < 96; idx += 64) {
    const int r = idx >> 1, half = idx & 1;
    *reinterpret_cast<uint4*>(g + r * 64 + 48 + half * 8) = make_uint4(0, 0, 0, 0);
  }
}

// ---- K-loop: LDS-staged, 2 buffers, counted vmcnt, TWO barriers per iter ----
// Invariants (m201): bar1 = "stage(t) landed everywhere" (each wave did
// vmcnt(SCNT) first); bar2 = "all waves' reads of buf[t&1] are in registers"
// (each wave did lgkmcnt(0) first) -> overwriting buf[t&1] is safe.
// stage(t+1), stage(t+2) stay in flight across barriers (never drained).
#define BUFO 7168   // ushorts per stage buffer
template <int MLIM, int SCNT>
__device__ __forceinline__ void kloopS(const unsigned short* __restrict__ sSrc,
                                       unsigned short* __restrict__ sDstBase,
                                       const size_t sK32,
                                       const unsigned short* __restrict__ aLds,
                                       const unsigned short* __restrict__ bLds,
                                       f32x4 (&acc)[3][4]) {
  auto stage = [&](int k32, int buf) __attribute__((always_inline)) {
#pragma unroll
    for (int j = 0; j < SCNT; ++j)
      gll16(sSrc + (size_t)k32 * sK32 + j * 512, sDstBase + buf * BUFO + j * 512);
  };
  bf16x8 fb[3], fa[MLIM];
  auto loadRegs = [&](int bt) __attribute__((always_inline)) {
#pragma unroll
    for (int nt = 0; nt < 3; ++nt)
      fb[nt] = *reinterpret_cast<const bf16x8*>(bLds + bt * BUFO + nt * 512);
#pragma unroll
    for (int mt = 0; mt < MLIM; ++mt)
      fa[mt] = *reinterpret_cast<const bf16x8*>(aLds + bt * BUFO + mt * 512);
  };
  auto mfma = [&]() __attribute__((always_inline)) {
#pragma unroll
    for (int mt = 0; mt < MLIM; ++mt)
#pragma unroll
      for (int nt = 0; nt < 3; ++nt)
        acc[nt][mt] = __builtin_amdgcn_mfma_f32_16x16x32_bf16(fb[nt], fa[mt], acc[nt][mt], 0, 0, 0);
  };
  stage(0, 0);
  stage(1, 1);
#pragma unroll 2
  for (int t = 0; t < 30; ++t) {
    waitcnt_vm<SCNT>();                  // own stage(t) landed (stage(t+1) in flight)
    __builtin_amdgcn_s_barrier();        // bar1: ALL stage(t) landed
    __builtin_amdgcn_sched_barrier(0);
    loadRegs(t & 1);                     // ds_read k32=t operands
    asm volatile("s_waitcnt lgkmcnt(0)" ::: "memory");   // my reads in regs
    __builtin_amdgcn_sched_barrier(0);   // rule #18: nothing hoists above
    __builtin_amdgcn_s_barrier();        // bar2: ALL reads of buf[t&1] done
    __builtin_amdgcn_sched_barrier(0);   // pin stage issue below bar2
    stage(t + 2, t & 1);                 // safe overwrite; stays in flight
    mfma();
  }
  // t=30: outstanding = stage(30)+stage(31) -> vmcnt(SCNT) completes stage(30)
  waitcnt_vm<SCNT>();
  __builtin_amdgcn_s_barrier();
  __builtin_amdgcn_sched_barrier(0);
  loadRegs(0);
  asm volatile("s_waitcnt lgkmcnt(0)" ::: "memory");
  __builtin_amdgcn_sched_barrier(0);
  mfma();
  // t=31: outstanding = stage(31) only -> vmcnt(0)
  waitcnt_vm<0>();
  __builtin_amdgcn_s_barrier();
  __builtin_amdgcn_sched_barrier(0);
  loadRegs(1);
  asm volatile("s_waitcnt lgkmcnt(0)" ::: "memory");
  __builtin_amdgcn_sched_barrier(0);
  mfma();
}

// ---- main fused kernel ----
// Grid (I/2, C/2), block 256 = 4 waves: wave wv -> (cap wv&1 of sorted pair,
// img i0+(wv>>1)). XCD swizzle: each XCD owns a 16-wide image-pair stripe.
__launch_bounds__(256, 3)
__global__ void k_main(const unsigned short* __restrict__ qbfF,
                       const unsigned short* __restrict__ ibfF,
                       const float* __restrict__ w1,
                       const unsigned short* __restrict__ gbf,
                       const float* __restrict__ gdiag,
                       const int* __restrict__ cap_lens,
                       const int* __restrict__ perm,
                       float* __restrict__ out) {
  __shared__ union {
    unsigned short stg[2][BUFO];      // [2buf][capA 4t | capB 4t | img0 3t | img1 3t] = 28672 B
    unsigned short attn[4][4096];     // post-loop: bf16 [w][r] per wave, 32768 B
  } u;
  __shared__ float w12s[4][64], w2ds[4][64], w2xs[4][64];   // 3072 B -> total 35840
  const int tid = threadIdx.x;
  const int lane = tid & 63;
  const int wv = tid >> 6;
  const int l15 = lane & 15;
  const int quad = lane >> 4;
  // ---- XCD-aware swizzle (16384 blocks, %8==0 -> bijective) ----
  const int flat = blockIdx.y * (NIMG / 2) + blockIdx.x;
  const int xcd = flat & 7;
  const int idx = flat >> 3;
  const int bx = xcd * 16 + (idx & 15);
  const int by = idx >> 4;
  const int i0 = bx * 2;
  const int cA = perm[2 * by], cB = perm[2 * by + 1];
  const int c = (wv & 1) ? cB : cA;
  const int img = i0 + (wv >> 1);
  const int clen = cap_lens[c];
  const int mlim = (clen + 15) >> 4;   // 1..4 valid w-tiles (this wave)

  // stage role: wv0->capA (own cap, mlim tiles), wv1->capB, wv2->img0, wv3->img1
  const unsigned short* sSrc;
  unsigned short* sDstBase;
  size_t sK32;
  if (wv == 0) {
    sSrc = qbfF + (size_t)cA * 32 * 4 * 512; sDstBase = &u.stg[0][0]; sK32 = 4 * 512;
  } else if (wv == 1) {
    sSrc = qbfF + (size_t)cB * 32 * 4 * 512; sDstBase = &u.stg[0][2048]; sK32 = 4 * 512;
  } else if (wv == 2) {
    sSrc = ibfF + (size_t)i0 * 32 * 3 * 512; sDstBase = &u.stg[0][4096]; sK32 = 3 * 512;
  } else {
    sSrc = ibfF + (size_t)(i0 + 1) * 32 * 3 * 512; sDstBase = &u.stg[0][5632]; sK32 = 3 * 512;
  }
  sSrc += lane * 8;
  const unsigned short* aLds = &u.stg[0][(wv & 1) * 2048] + lane * 8;
  const unsigned short* bLds = &u.stg[0][4096 + (wv >> 1) * 1536] + lane * 8;

  f32x4 acc[3][4];
  const f32x4 zero4 = {0.f, 0.f, 0.f, 0.f};
#pragma unroll
  for (int nt = 0; nt < 3; ++nt)
#pragma unroll
    for (int mt = 0; mt < 4; ++mt) acc[nt][mt] = zero4;

  // 8 variants, all execute exactly 62 anonymous barriers -> waves pair up.
  if (wv < 2) {
    switch (mlim) {   // cap stager: SCNT = own mlim
      case 1: kloopS<1, 1>(sSrc, sDstBase, sK32, aLds, bLds, acc); break;
      case 2: kloopS<2, 2>(sSrc, sDstBase, sK32, aLds, bLds, acc); break;
      case 3: kloopS<3, 3>(sSrc, sDstBase, sK32, aLds, bLds, acc); break;
      default: kloopS<4, 4>(sSrc, sDstBase, sK32, aLds, bLds, acc); break;
    }
  } else {
    switch (mlim) {   // img stager: SCNT = 3
      case 1: kloopS<1, 3>(sSrc, sDstBase, sK32, aLds, bLds, acc); break;
      case 2: kloopS<2, 3>(sSrc, sDstBase, sK32, aLds, bLds, acc); break;
      case 3: kloopS<3, 3>(sSrc, sDstBase, sK32, aLds, bLds, acc); break;
      default: kloopS<4, 3>(sSrc, sDstBase, sK32, aLds, bLds, acc); break;
    }
  }
  __syncthreads();   // full drain; union -> attn reuse safe

  {
    uint4* ab = reinterpret_cast<uint4*>(&u.attn[wv][0]);
    const uint4 z4 = make_uint4(0, 0, 0, 0);
    for (int j = lane; j < 512; j += 64) ab[j] = z4;   // zero all (incl. pad groups)
  }

  // exact diag per register row r = nt*16 + quad*4 + rg
  const float* dg = gdiag + (size_t)img * 48;
  float dv[3][4];
#pragma unroll
  for (int nt = 0; nt < 3; ++nt)
#pragma unroll
    for (int rg = 0; rg < 4; ++rg)
      dv[nt][rg] = dg[nt * 16 + quad * 4 + rg];

  // pass 1: per-region l2 norm over w -> scale (w = lane dim: in-reg over mt,
  // then xor1..8; 12 independent butterflies, ILP-overlapped)
  float scale[3][4];
#pragma unroll
  for (int nt = 0; nt < 3; ++nt)
#pragma unroll
    for (int rg = 0; rg < 4; ++rg) {
      float p = 0.f;
#pragma unroll
      for (int mt = 0; mt < 4; ++mt)
        if (mt < mlim) {
          const float s = acc[nt][mt][rg];
          const float l = s < 0.f ? 0.1f * s : s;
          p += l * l;
        }
      p += __shfl_xor(p, 1); p += __shfl_xor(p, 2);
      p += __shfl_xor(p, 4); p += __shfl_xor(p, 8);
      scale[nt][rg] = 9.0f / (sqrtf(p) + 1e-8f);   // SMOOTH folded in
    }

  // pass 2: softmax over r per w-column. |t| <= 9 -> no max subtraction.
  // Invalid r (>=36): nt==2 && quad!=0 -> e=0. Normalized attn packed as bf16
  // pairs in 24 u32 regs (bit-identical to the LDS attn values).
  unsigned a_pk[4][3][2];
#pragma unroll
  for (int mt = 0; mt < 4; ++mt) {
    if (mt >= mlim) continue;
    float ee[3][4];
    float sm = 0.f, wp = 0.f, dd = 0.f;
#pragma unroll
    for (int nt = 0; nt < 3; ++nt) {
      const bool rvalid = (nt < 2) || (quad == 0);
#pragma unroll
      for (int rg = 0; rg < 4; ++rg) {
        const float s = acc[nt][mt][rg];
        const float l = s < 0.f ? 0.1f * s : s;
        const float e0 = rvalid ? __expf(l * scale[nt][rg]) : 0.f;
        ee[nt][rg] = e0;
        sm += e0;
        wp += e0 * s;                       // w12 uses RAW s
        dd += e0 * e0 * dv[nt][rg];         // exact diag term
      }
    }
    sm += __shfl_xor(sm, 16); sm += __shfl_xor(sm, 32);
    wp += __shfl_xor(wp, 16); wp += __shfl_xor(wp, 32);
    dd += __shfl_xor(dd, 16); dd += __shfl_xor(dd, 32);
    const float inv = 1.0f / sm;
    const int w = mt * 16 + l15;
    const int key = l15 & 7;
    unsigned short* arow = &u.attn[wv][w * 64];
#pragma unroll
    for (int nt = 0; nt < 3; ++nt)
#pragma unroll
      for (int pr = 0; pr < 2; ++pr) {
        const unsigned b0 = f2bf(ee[nt][2 * pr] * inv);
        const unsigned b1 = f2bf(ee[nt][2 * pr + 1] * inv);
        const unsigned pk = b0 | (b1 << 16);
        a_pk[mt][nt][pr] = pk;
        // r0 = nt*16+quad*4+2pr (even), r1 = r0+1: same 8-group, adjacent ->
        // one aligned u32 LDS store.
        const int r0 = nt * 16 + quad * 4 + 2 * pr;
        *reinterpret_cast<unsigned*>(&arow[(((r0 >> 3) ^ key) << 3) + (r0 & 7)]) = pk;
      }
    if (quad == 0) { w12s[wv][w] = wp * inv; w2ds[wv][w] = dd * inv * inv; }
  }

  // Yt = G x Attn^T via MFMA (A=G rows r, B=attn cols w) -> Yt[nt][rg] at lane
  // (l15,quad) = Y[r = nt*16+quad*4+rg][w = mt*16+l15]: SAME layout as a_pk.
  bf16x8 gfrag[3][2];
#pragma unroll
  for (int nt = 0; nt < 3; ++nt)
#pragma unroll
    for (int ks = 0; ks < 2; ++ks)
      gfrag[nt][ks] = *reinterpret_cast<const bf16x8*>(
          gbf + ((size_t)img * 48 + nt * 16 + l15) * 64 + ((ks * 4 + quad) << 3));
#pragma unroll
  for (int mt = 0; mt < 4; ++mt) {
    if (mt >= mlim) continue;
    bf16x8 af[2];
#pragma unroll
    for (int ks = 0; ks < 2; ++ks)
      af[ks] = *reinterpret_cast<const bf16x8*>(
          &u.attn[wv][(mt * 16 + l15) * 64 + (((ks * 4 + quad) ^ (l15 & 7)) << 3)]);
    f32x4 Yt[3] = {zero4, zero4, zero4};
#pragma unroll
    for (int nt = 0; nt < 3; ++nt)
#pragma unroll
      for (int ks = 0; ks < 2; ++ks)
        Yt[nt] = __builtin_amdgcn_mfma_f32_16x16x32_bf16(gfrag[nt][ks], af[ks], Yt[nt], 0, 0, 0);
    // cross term: w2x[w] = sum_r a[w][r] * Y[r][w]; a unpacked from bf16 pairs
    float p = 0.f;
#pragma unroll
    for (int nt = 0; nt < 3; ++nt)
#pragma unroll
      for (int pr = 0; pr < 2; ++pr) {
        const unsigned pk = a_pk[mt][nt][pr];
        const float a0 = __uint_as_float(pk << 16);
        const float a1 = __uint_as_float(pk & 0xffff0000u);
        p += a0 * Yt[nt][2 * pr] + a1 * Yt[nt][2 * pr + 1];
      }
    p += __shfl_xor(p, 16); p += __shfl_xor(p, 32);
    if (quad == 0) w2xs[wv][mt * 16 + l15] = p;
  }

  // final: lane = word
  float simv = 0.f;
  if (lane < clen) {
    const float w2sq = fmaxf(w2xs[wv][lane] + w2ds[wv][lane], 0.f);
    const float w2v = sqrtf(w2sq);
    const float w12v = w12s[wv][lane];
    const float w1v = w1[(size_t)c * WPAD + lane];
    simv = w12v / fmaxf(w1v * w2v, 1e-8f);
  }
  simv += __shfl_xor(simv, 1);
  simv += __shfl_xor(simv, 2);
  simv += __shfl_xor(simv, 4);
  simv += __shfl_xor(simv, 8);
  simv += __shfl_xor(simv, 16);
  simv += __shfl_xor(simv, 32);
  if (lane == 0) out[(size_t)img * NCAP + c] = simv / (float)clen;
}

extern "C" void kernel_launch(void* const* d_in, const int* in_sizes, int n_in,
                              void* d_out, int out_size, void* d_ws, size_t ws_size,
                              hipStream_t stream) {
  const float* imgs = (const float*)d_in[0];
  const float* caps = (const float*)d_in[1];
  const int* cap_lens = (const int*)d_in[3];   // img_lens (d_in[2]) unused by reference
  float* out = (float*)d_out;

  char* ws = (char*)d_ws;
  const size_t QBF_B = (size_t)NCAP * 32 * 4 * 512 * 2;      // 33,554,432
  const size_t IBF_B = (size_t)NIMG * 32 * 3 * 512 * 2;      // 25,165,824
  const size_t W1_B = (size_t)NCAP * WPAD * 4;               // 65,536
  const size_t GBF_B = (size_t)NIMG * 48 * 64 * 2;           // 1,572,864
  const size_t GD_B = (size_t)NIMG * 48 * 4;                 // 49,152
  unsigned short* qbfF = (unsigned short*)ws;
  unsigned short* ibfF = (unsigned short*)(ws + QBF_B);
  float* w1 = (float*)(ws + QBF_B + IBF_B);
  unsigned short* gbf = (unsigned short*)(ws + QBF_B + IBF_B + W1_B);
  float* gdiag = (float*)(ws + QBF_B + IBF_B + W1_B + GBF_B);
  int* perm = (int*)(ws + QBF_B + IBF_B + W1_B + GBF_B + GD_B);

  k_prep_w1<<<NCAP * WPAD, 256, 0, stream>>>(caps, cap_lens, w1);
  k_sort<<<1, NCAP, 0, stream>>>(cap_lens, perm);
  k_prep_caps_frag<<<dim3(32, NCAP), 256, 0, stream>>>(caps, cap_lens, qbfF);
  k_prep_imgs_frag<<<dim3(32, NIMG), 192, 0, stream>>>(imgs, ibfF);
  k_gram_mfma<<<NIMG, 64, 0, stream>>>(imgs, ibfF, gbf, gdiag);
  k_main<<<dim3(NIMG / 2, NCAP / 2), 256, 0, stream>>>(qbfF, ibfF, w1, gbf, gdiag, cap_lens, perm, out);
}

// Round 9
// 533.196 us; speedup vs baseline: 1.2441x; 1.0343x over previous
//
#include <hip/hip_runtime.h>

// T2ICrossAttentionPool on MI355X.
// Identities: w12[c,i,w] = sum_r attn*Sraw;  |wctx|^2 = a^T G a with
//   G = exact fp32 diag (register math) + off-diag G' bf16 (MFMA quadratic form).
// R13: transposed epilogue, depth-3 register K-loop, (256,3): 433us k_main.
// R14-R18 (staging arc, CLOSED): LDS-staged K-loop. Best variant (R18,
//   two-barrier counted-vmcnt, race-free) = 460us: LDS pipe becomes the top
//   consumer (~70%) and 64 barriers/loop lock-step waves against it. Tiles
//   too small (6-7KB/k32) to amortize staging. Register pipeline wins.
// R19: revert to R13 K-loop + R18's packed epilogue (proven correct, -24 regs
//   peak pressure) + prep cut: w1 fused into caps_frag (partial sum-of-squares
//   + atomicAdd; k_sort zeroes the buffer each launch -> replay-idempotent;
//   sqrt at use in k_main). 4 prep launches instead of 5.

#define NIMG 256
#define NREG 36
#define DIM 1024
#define NCAP 256
#define MAXW 60
#define WPAD 64

typedef short bf16x8 __attribute__((ext_vector_type(8)));
typedef float f32x4 __attribute__((ext_vector_type(4)));

__device__ __forceinline__ unsigned short f2bf(float f) {
  unsigned u = __float_as_uint(f);
  u += 0x7FFF + ((u >> 16) & 1);   // round-to-nearest-even
  return (unsigned short)(u >> 16);
}

// ---- prep: caption permutation sorted by length (rank-count) + zero w1sq ----
// Zeroing here makes the caps_frag atomicAdd accumulation replay-idempotent.
__global__ void k_sort(const int* __restrict__ cap_lens, int* __restrict__ perm,
                       float* __restrict__ w1sq) {
  const int i = threadIdx.x;           // 256 threads
#pragma unroll
  for (int j = 0; j < WPAD; ++j) w1sq[i * WPAD + j] = 0.f;
  const int li = cap_lens[i];
  int r = 0;
  for (int j = 0; j < NCAP; ++j) {
    const int lj = cap_lens[j];
    r += (lj < li) || (lj == li && j < i);
  }
  perm[r] = i;
}

// ---- prep: caps -> fragments, masked (rows w>=clen zero); fused w1 partial ----
// Layout: qbfF[(((c*32 + k32)*4 + mt)*64 + lane)*8 + j]
//   = q[c][m = mt*16 + (lane&15)][k = k32*32 + (lane>>4)*8 + j]
// w1sq[c][m] += sum_k(q^2) over this block's 32-k slice (fp32, pre-bf16).
__global__ void k_prep_caps_frag(const float* __restrict__ caps, const int* __restrict__ cap_lens,
                                 unsigned short* __restrict__ qbfF,
                                 float* __restrict__ w1sq) {
  const int k32 = blockIdx.x;
  const int c = blockIdx.y;
  const int t = threadIdx.x;
  const int mt = t >> 6;
  const int lane = t & 63;
  const int m = mt * 16 + (lane & 15);
  const int k0 = k32 * 32 + (lane >> 4) * 8;
  const int clen = cap_lens[c];
  float4 v0 = make_float4(0.f, 0.f, 0.f, 0.f), v1 = v0;
  if (m < clen && m < MAXW) {
    const float* src = caps + ((size_t)c * MAXW + m) * DIM + k0;
    v0 = *reinterpret_cast<const float4*>(src);
    v1 = *reinterpret_cast<const float4*>(src + 4);
  }
  float ss = v0.x * v0.x + v0.y * v0.y + v0.z * v0.z + v0.w * v0.w
           + v1.x * v1.x + v1.y * v1.y + v1.z * v1.z + v1.w * v1.w;
  ss += __shfl_xor(ss, 16);
  ss += __shfl_xor(ss, 32);
  if ((lane >> 4) == 0 && ss != 0.f) atomicAdd(&w1sq[(size_t)c * WPAD + m], ss);
  ushort4 o0, o1;
  o0.x = f2bf(v0.x); o0.y = f2bf(v0.y); o0.z = f2bf(v0.z); o0.w = f2bf(v0.w);
  o1.x = f2bf(v1.x); o1.y = f2bf(v1.y); o1.z = f2bf(v1.z); o1.w = f2bf(v1.w);
  unsigned short* dst = qbfF + ((size_t)(((c * 32 + k32) * 4 + mt) * 64 + lane)) * 8;
  *reinterpret_cast<ushort4*>(dst) = o0;
  *reinterpret_cast<ushort4*>(dst + 4) = o1;
}

// ---- prep: imgs -> fragments (rows r>=36 zero) ----
// Layout: ibfF[(((i*32 + k32)*3 + nt)*64 + lane)*8 + j]
//   = imgs[i][r = nt*16 + (lane&15)][k = k32*32 + (lane>>4)*8 + j]
__global__ void k_prep_imgs_frag(const float* __restrict__ imgs,
                                 unsigned short* __restrict__ ibfF) {
  const int k32 = blockIdx.x;
  const int i = blockIdx.y;
  const int t = threadIdx.x;          // 0..191
  const int nt = t >> 6;
  const int lane = t & 63;
  const int r = nt * 16 + (lane & 15);
  const int k0 = k32 * 32 + (lane >> 4) * 8;
  float4 v0 = make_float4(0.f, 0.f, 0.f, 0.f), v1 = v0;
  if (r < NREG) {
    const float* src = imgs + ((size_t)i * NREG + r) * DIM + k0;
    v0 = *reinterpret_cast<const float4*>(src);
    v1 = *reinterpret_cast<const float4*>(src + 4);
  }
  ushort4 o0, o1;
  o0.x = f2bf(v0.x); o0.y = f2bf(v0.y); o0.z = f2bf(v0.z); o0.w = f2bf(v0.w);
  o1.x = f2bf(v1.x); o1.y = f2bf(v1.y); o1.z = f2bf(v1.z); o1.w = f2bf(v1.w);
  unsigned short* dst = ibfF + ((size_t)(((i * 32 + k32) * 3 + nt) * 64 + lane)) * 8;
  *reinterpret_cast<ushort4*>(dst) = o0;
  *reinterpret_cast<ushort4*>(dst + 4) = o1;
}

// ---- Gram via MFMA: one wave per image (same ibfF line feeds both operands) ----
__global__ void k_gram_mfma(const float* __restrict__ imgs,
                            const unsigned short* __restrict__ ibfF,
                            unsigned short* __restrict__ gbf,
                            float* __restrict__ gdiag) {
  const int i = blockIdx.x;
  const int lane = threadIdx.x & 63;
  const int l15 = lane & 15;
  const int quad = lane >> 4;

  // exact fp32 diag: rows r0+quad, k split across the 16 lanes of each quad
  float* dg = gdiag + (size_t)i * 48;
#pragma unroll
  for (int r0 = 0; r0 < 36; r0 += 4) {
    const int r = r0 + quad;
    const float* row = imgs + ((size_t)i * NREG + r) * DIM;
    float ss = 0.f;
#pragma unroll
    for (int p = 0; p < 16; ++p) {
      float4 v = *reinterpret_cast<const float4*>(row + p * 64 + l15 * 4);
      ss += v.x * v.x + v.y * v.y + v.z * v.z + v.w * v.w;
    }
    ss += __shfl_xor(ss, 1); ss += __shfl_xor(ss, 2);
    ss += __shfl_xor(ss, 4); ss += __shfl_xor(ss, 8);
    if (l15 == 0) dg[r] = ss;
  }
  if (lane < 12) dg[36 + lane] = 0.f;

  const unsigned short* base = ibfF + ((size_t)i * 32 * 3) * 512 + lane * 8;
  const f32x4 zero4 = {0.f, 0.f, 0.f, 0.f};
  f32x4 acc[3][3];
#pragma unroll
  for (int na = 0; na < 3; ++na)
#pragma unroll
    for (int nb = 0; nb < 3; ++nb) acc[na][nb] = zero4;
  bf16x8 f[2][3];
#pragma unroll
  for (int nt = 0; nt < 3; ++nt)
    f[0][nt] = *reinterpret_cast<const bf16x8*>(base + (size_t)nt * 512);
#pragma unroll
  for (int k32 = 0; k32 < 32; ++k32) {
    if (k32 + 1 < 32) {
      const int nb_ = (k32 + 1) & 1;
#pragma unroll
      for (int nt = 0; nt < 3; ++nt)
        f[nb_][nt] = *reinterpret_cast<const bf16x8*>(base + ((size_t)(k32 + 1) * 3 + nt) * 512);
    }
    const int b = k32 & 1;
#pragma unroll
    for (int na = 0; na < 3; ++na)
#pragma unroll
      for (int nb = 0; nb < 3; ++nb)
        acc[na][nb] = __builtin_amdgcn_mfma_f32_16x16x32_bf16(f[b][na], f[b][nb], acc[na][nb], 0, 0, 0);
  }
  unsigned short* g = gbf + (size_t)i * (48 * 64);
#pragma unroll
  for (int na = 0; na < 3; ++na)
#pragma unroll
    for (int nb = 0; nb < 3; ++nb)
#pragma unroll
      for (int rg = 0; rg < 4; ++rg) {
        const int r = na * 16 + quad * 4 + rg;   // C row
        const int c = nb * 16 + l15;             // C col
        g[r * 64 + c] = (r == c) ? (unsigned short)0 : f2bf(acc[na][nb][rg]);
      }
  // zero the K-pad cols 48..63 (16 ushorts = 2 uint4 per row)
  for (int idx = lane; idx < 96; idx += 64) {
    const int r = idx >> 1, half = idx & 1;
    *reinterpret_cast<uint4*>(g + r * 64 + 48 + half * 8) = make_uint4(0, 0, 0, 0);
  }
}

// ---- K-loop: S^T = imgs x caps^T, depth-3 register pipeline (R13 winner) ----
// A-op = ibfF (3 nt tiles), B-op = qbfF (MLIM mt tiles); acc[nt][mt]:
// col = w (l15), row = r (quad*4+rg). sched_barrier(0) pins prefetch issue.
template <int MLIM>
__device__ __forceinline__ void kloopT(const unsigned short* __restrict__ aBase,  // caps
                                       const unsigned short* __restrict__ bBase,  // imgs
                                       f32x4 (&acc)[3][4]) {
  bf16x8 fa[3][MLIM], fb[3][3];
  auto load = [&](int k32, int buf) __attribute__((always_inline)) {
#pragma unroll
    for (int nt = 0; nt < 3; ++nt)
      fb[buf][nt] = *reinterpret_cast<const bf16x8*>(bBase + ((size_t)k32 * 3 + nt) * 512);
#pragma unroll
    for (int mt = 0; mt < MLIM; ++mt)
      fa[buf][mt] = *reinterpret_cast<const bf16x8*>(aBase + ((size_t)k32 * 4 + mt) * 512);
  };
  auto compute = [&](int buf) __attribute__((always_inline)) {
#pragma unroll
    for (int mt = 0; mt < MLIM; ++mt)
#pragma unroll
      for (int nt = 0; nt < 3; ++nt)
        acc[nt][mt] = __builtin_amdgcn_mfma_f32_16x16x32_bf16(fb[buf][nt], fa[buf][mt], acc[nt][mt], 0, 0, 0);
  };
  load(0, 0);
  load(1, 1);
#pragma unroll
  for (int k32 = 0; k32 < 32; ++k32) {
    if (k32 + 2 < 32) load(k32 + 2, (k32 + 2) % 3);
    __builtin_amdgcn_sched_barrier(0);   // pin: prefetch issued above, MFMAs stay below
    compute(k32 % 3);
  }
}

// ---- main fused kernel ----
// Grid (I/2, C/2), block 256 = 4 waves: wave wv -> (cap wv&1 of sorted pair,
// img i0+(wv>>1)); wave pairs share A/B fragment lines via L1.
// XCD swizzle: each XCD owns a 16-wide image-pair stripe.
__launch_bounds__(256, 3)
__global__ void k_main(const unsigned short* __restrict__ qbfF,
                       const unsigned short* __restrict__ ibfF,
                       const float* __restrict__ w1sq,
                       const unsigned short* __restrict__ gbf,
                       const float* __restrict__ gdiag,
                       const int* __restrict__ cap_lens,
                       const int* __restrict__ perm,
                       float* __restrict__ out) {
  __shared__ struct {
    unsigned short attn[4][4096];     // bf16 [w][r], r-groups XOR-swizzled by l15&7
    float w12[4][64];
    float w2d[4][64];
    float w2x[4][64];
  } lds;                               // 35840 B
  const int tid = threadIdx.x;
  const int lane = tid & 63;
  const int wv = tid >> 6;
  const int l15 = lane & 15;
  const int quad = lane >> 4;
  // ---- XCD-aware swizzle (16384 blocks, %8==0 -> bijective) ----
  const int flat = blockIdx.y * (NIMG / 2) + blockIdx.x;
  const int xcd = flat & 7;
  const int idx = flat >> 3;
  const int bx = xcd * 16 + (idx & 15);
  const int by = idx >> 4;
  const int i0 = bx * 2;
  const int cA = perm[2 * by], cB = perm[2 * by + 1];
  const int c = (wv & 1) ? cB : cA;
  const int img = i0 + (wv >> 1);
  const int clen = cap_lens[c];
  const int mlim = (clen + 15) >> 4;   // 1..4 valid w-tiles

  f32x4 acc[3][4];
  const f32x4 zero4 = {0.f, 0.f, 0.f, 0.f};
#pragma unroll
  for (int nt = 0; nt < 3; ++nt)
#pragma unroll
    for (int mt = 0; mt < 4; ++mt) acc[nt][mt] = zero4;

  const unsigned short* aBase = qbfF + ((size_t)c * 32 * 4) * 512 + lane * 8;
  const unsigned short* bBase = ibfF + ((size_t)img * 32 * 3) * 512 + lane * 8;

  switch (mlim) {
    case 1: kloopT<1>(aBase, bBase, acc); break;
    case 2: kloopT<2>(aBase, bBase, acc); break;
    case 3: kloopT<3>(aBase, bBase, acc); break;
    default: kloopT<4>(aBase, bBase, acc); break;
  }

  // ---- epilogue (wave-private LDS; in-wave lgkmcnt ordering suffices) ----
  {
    uint4* ab = reinterpret_cast<uint4*>(&lds.attn[wv][0]);
    const uint4 z4 = make_uint4(0, 0, 0, 0);
    for (int j = lane; j < 512; j += 64) ab[j] = z4;   // zero all (incl. pad groups)
  }

  // exact diag per register row r = nt*16 + quad*4 + rg
  const float* dg = gdiag + (size_t)img * 48;
  float dv[3][4];
#pragma unroll
  for (int nt = 0; nt < 3; ++nt)
#pragma unroll
    for (int rg = 0; rg < 4; ++rg)
      dv[nt][rg] = dg[nt * 16 + quad * 4 + rg];

  // pass 1: per-region l2 norm over w -> scale (in-reg over mt, then xor1..8)
  float scale[3][4];
#pragma unroll
  for (int nt = 0; nt < 3; ++nt)
#pragma unroll
    for (int rg = 0; rg < 4; ++rg) {
      float p = 0.f;
#pragma unroll
      for (int mt = 0; mt < 4; ++mt)
        if (mt < mlim) {
          const float s = acc[nt][mt][rg];
          const float l = s < 0.f ? 0.1f * s : s;
          p += l * l;
        }
      p += __shfl_xor(p, 1); p += __shfl_xor(p, 2);
      p += __shfl_xor(p, 4); p += __shfl_xor(p, 8);
      scale[nt][rg] = 9.0f / (sqrtf(p) + 1e-8f);   // SMOOTH folded in
    }

  // pass 2: softmax over r per w-column. |t| <= 9 -> no max subtraction.
  // Invalid r (>=36): nt==2 && quad!=0 -> e=0. Normalized attn packed as bf16
  // pairs in 24 u32 regs (bit-identical to the LDS attn values).
  unsigned a_pk[4][3][2];
#pragma unroll
  for (int mt = 0; mt < 4; ++mt) {
    if (mt >= mlim) continue;
    float ee[3][4];
    float sm = 0.f, wp = 0.f, dd = 0.f;
#pragma unroll
    for (int nt = 0; nt < 3; ++nt) {
      const bool rvalid = (nt < 2) || (quad == 0);
#pragma unroll
      for (int rg = 0; rg < 4; ++rg) {
        const float s = acc[nt][mt][rg];
        const float l = s < 0.f ? 0.1f * s : s;
        const float e0 = rvalid ? __expf(l * scale[nt][rg]) : 0.f;
        ee[nt][rg] = e0;
        sm += e0;
        wp += e0 * s;                       // w12 uses RAW s
        dd += e0 * e0 * dv[nt][rg];         // exact diag term
      }
    }
    sm += __shfl_xor(sm, 16); sm += __shfl_xor(sm, 32);
    wp += __shfl_xor(wp, 16); wp += __shfl_xor(wp, 32);
    dd += __shfl_xor(dd, 16); dd += __shfl_xor(dd, 32);
    const float inv = 1.0f / sm;
    const int w = mt * 16 + l15;
    const int key = l15 & 7;
    unsigned short* arow = &lds.attn[wv][w * 64];
#pragma unroll
    for (int nt = 0; nt < 3; ++nt)
#pragma unroll
      for (int pr = 0; pr < 2; ++pr) {
        const unsigned b0 = f2bf(ee[nt][2 * pr] * inv);
        const unsigned b1 = f2bf(ee[nt][2 * pr + 1] * inv);
        const unsigned pk = b0 | (b1 << 16);
        a_pk[mt][nt][pr] = pk;
        // r0 even, r1 = r0+1: same 8-group, adjacent -> one aligned u32 store
        const int r0 = nt * 16 + quad * 4 + 2 * pr;
        *reinterpret_cast<unsigned*>(&arow[(((r0 >> 3) ^ key) << 3) + (r0 & 7)]) = pk;
      }
    if (quad == 0) { lds.w12[wv][w] = wp * inv; lds.w2d[wv][w] = dd * inv * inv; }
  }

  // Yt = G x Attn^T via MFMA (A=G rows r, B=attn cols w) -> Yt[nt][rg] at lane
  // (l15,quad) = Y[r = nt*16+quad*4+rg][w = mt*16+l15]: SAME layout as a_pk.
  bf16x8 gfrag[3][2];
#pragma unroll
  for (int nt = 0; nt < 3; ++nt)
#pragma unroll
    for (int ks = 0; ks < 2; ++ks)
      gfrag[nt][ks] = *reinterpret_cast<const bf16x8*>(
          gbf + ((size_t)img * 48 + nt * 16 + l15) * 64 + ((ks * 4 + quad) << 3));
#pragma unroll
  for (int mt = 0; mt < 4; ++mt) {
    if (mt >= mlim) continue;
    bf16x8 af[2];
#pragma unroll
    for (int ks = 0; ks < 2; ++ks)
      af[ks] = *reinterpret_cast<const bf16x8*>(
          &lds.attn[wv][(mt * 16 + l15) * 64 + (((ks * 4 + quad) ^ (l15 & 7)) << 3)]);
    f32x4 Yt[3] = {zero4, zero4, zero4};
#pragma unroll
    for (int nt = 0; nt < 3; ++nt)
#pragma unroll
      for (int ks = 0; ks < 2; ++ks)
        Yt[nt] = __builtin_amdgcn_mfma_f32_16x16x32_bf16(gfrag[nt][ks], af[ks], Yt[nt], 0, 0, 0);
    // cross term: w2x[w] = sum_r a[w][r] * Y[r][w]; a unpacked from bf16 pairs
    float p = 0.f;
#pragma unroll
    for (int nt = 0; nt < 3; ++nt)
#pragma unroll
      for (int pr = 0; pr < 2; ++pr) {
        const unsigned pk = a_pk[mt][nt][pr];
        const float a0 = __uint_as_float(pk << 16);
        const float a1 = __uint_as_float(pk & 0xffff0000u);
        p += a0 * Yt[nt][2 * pr] + a1 * Yt[nt][2 * pr + 1];
      }
    p += __shfl_xor(p, 16); p += __shfl_xor(p, 32);
    if (quad == 0) lds.w2x[wv][mt * 16 + l15] = p;
  }

  // final: lane = word
  float simv = 0.f;
  if (lane < clen) {
    const float w2sq = fmaxf(lds.w2x[wv][lane] + lds.w2d[wv][lane], 0.f);
    const float w2v = sqrtf(w2sq);
    const float w12v = lds.w12[wv][lane];
    const float w1v = sqrtf(w1sq[(size_t)c * WPAD + lane]);
    simv = w12v / fmaxf(w1v * w2v, 1e-8f);
  }
  simv += __shfl_xor(simv, 1);
  simv += __shfl_xor(simv, 2);
  simv += __shfl_xor(simv, 4);
  simv += __shfl_xor(simv, 8);
  simv += __shfl_xor(simv, 16);
  simv += __shfl_xor(simv, 32);
  if (lane == 0) out[(size_t)img * NCAP + c] = simv / (float)clen;
}

extern "C" void kernel_launch(void* const* d_in, const int* in_sizes, int n_in,
                              void* d_out, int out_size, void* d_ws, size_t ws_size,
                              hipStream_t stream) {
  const float* imgs = (const float*)d_in[0];
  const float* caps = (const float*)d_in[1];
  const int* cap_lens = (const int*)d_in[3];   // img_lens (d_in[2]) unused by reference
  float* out = (float*)d_out;

  char* ws = (char*)d_ws;
  const size_t QBF_B = (size_t)NCAP * 32 * 4 * 512 * 2;      // 33,554,432
  const size_t IBF_B = (size_t)NIMG * 32 * 3 * 512 * 2;      // 25,165,824
  const size_t W1_B = (size_t)NCAP * WPAD * 4;               // 65,536
  const size_t GBF_B = (size_t)NIMG * 48 * 64 * 2;           // 1,572,864
  const size_t GD_B = (size_t)NIMG * 48 * 4;                 // 49,152
  unsigned short* qbfF = (unsigned short*)ws;
  unsigned short* ibfF = (unsigned short*)(ws + QBF_B);
  float* w1sq = (float*)(ws + QBF_B + IBF_B);
  unsigned short* gbf = (unsigned short*)(ws + QBF_B + IBF_B + W1_B);
  float* gdiag = (float*)(ws + QBF_B + IBF_B + W1_B + GBF_B);
  int* perm = (int*)(ws + QBF_B + IBF_B + W1_B + GBF_B + GD_B);

  k_sort<<<1, NCAP, 0, stream>>>(cap_lens, perm, w1sq);
  k_prep_caps_frag<<<dim3(32, NCAP), 256, 0, stream>>>(caps, cap_lens, qbfF, w1sq);
  k_prep_imgs_frag<<<dim3(32, NIMG), 192, 0, stream>>>(imgs, ibfF);
  k_gram_mfma<<<NIMG, 64, 0, stream>>>(imgs, ibfF, gbf, gdiag);
  k_main<<<dim3(NIMG / 2, NCAP / 2), 256, 0, stream>>>(qbfF, ibfF, w1sq, gbf, gdiag, cap_lens, perm, out);
}

// Round 10
// 530.294 us; speedup vs baseline: 1.2509x; 1.0055x over previous
//
#include <hip/hip_runtime.h>

// T2ICrossAttentionPool on MI355X.
// Identities: w12[c,i,w] = sum_r attn*Sraw;  |wctx|^2 = a^T G a with
//   G = exact fp32 diag (register math) + off-diag G' bf16 (MFMA quadratic form).
// R13/R19: transposed epilogue, depth-3 register K-loop, (256,3): ~433us k_main.
// R14-R18 (staging arc, CLOSED): LDS staging loses (best 460us) - barriers
//   lock-step waves against the shared LDS pipe; tiles too small to amortize.
// R20: K-loop address VALU -> SALU. c/img are wave-uniform but wv-derived, so
//   divergence analysis kept bases in VGPRs (v_lshl_add_u64 per load ~= half
//   of VALUBusy 48%). readfirstlane(c/img) proves uniformity -> saddr-form
//   loads: SGPR base + imm + lane*16 voffset; base advance on the SALU pipe.
//   Applied to K-loop + epilogue gbf/gdiag/w1sq bases. No structural change.

#define NIMG 256
#define NREG 36
#define DIM 1024
#define NCAP 256
#define MAXW 60
#define WPAD 64

typedef short bf16x8 __attribute__((ext_vector_type(8)));
typedef float f32x4 __attribute__((ext_vector_type(4)));

__device__ __forceinline__ unsigned short f2bf(float f) {
  unsigned u = __float_as_uint(f);
  u += 0x7FFF + ((u >> 16) & 1);   // round-to-nearest-even
  return (unsigned short)(u >> 16);
}

// ---- prep: caption permutation sorted by length (rank-count) + zero w1sq ----
// Zeroing here makes the caps_frag atomicAdd accumulation replay-idempotent.
__global__ void k_sort(const int* __restrict__ cap_lens, int* __restrict__ perm,
                       float* __restrict__ w1sq) {
  const int i = threadIdx.x;           // 256 threads
#pragma unroll
  for (int j = 0; j < WPAD; ++j) w1sq[i * WPAD + j] = 0.f;
  const int li = cap_lens[i];
  int r = 0;
  for (int j = 0; j < NCAP; ++j) {
    const int lj = cap_lens[j];
    r += (lj < li) || (lj == li && j < i);
  }
  perm[r] = i;
}

// ---- prep: caps -> fragments, masked (rows w>=clen zero); fused w1 partial ----
// Layout: qbfF[(((c*32 + k32)*4 + mt)*64 + lane)*8 + j]
//   = q[c][m = mt*16 + (lane&15)][k = k32*32 + (lane>>4)*8 + j]
// w1sq[c][m] += sum_k(q^2) over this block's 32-k slice (fp32, pre-bf16).
__global__ void k_prep_caps_frag(const float* __restrict__ caps, const int* __restrict__ cap_lens,
                                 unsigned short* __restrict__ qbfF,
                                 float* __restrict__ w1sq) {
  const int k32 = blockIdx.x;
  const int c = blockIdx.y;
  const int t = threadIdx.x;
  const int mt = t >> 6;
  const int lane = t & 63;
  const int m = mt * 16 + (lane & 15);
  const int k0 = k32 * 32 + (lane >> 4) * 8;
  const int clen = cap_lens[c];
  float4 v0 = make_float4(0.f, 0.f, 0.f, 0.f), v1 = v0;
  if (m < clen && m < MAXW) {
    const float* src = caps + ((size_t)c * MAXW + m) * DIM + k0;
    v0 = *reinterpret_cast<const float4*>(src);
    v1 = *reinterpret_cast<const float4*>(src + 4);
  }
  float ss = v0.x * v0.x + v0.y * v0.y + v0.z * v0.z + v0.w * v0.w
           + v1.x * v1.x + v1.y * v1.y + v1.z * v1.z + v1.w * v1.w;
  ss += __shfl_xor(ss, 16);
  ss += __shfl_xor(ss, 32);
  if ((lane >> 4) == 0 && ss != 0.f) atomicAdd(&w1sq[(size_t)c * WPAD + m], ss);
  ushort4 o0, o1;
  o0.x = f2bf(v0.x); o0.y = f2bf(v0.y); o0.z = f2bf(v0.z); o0.w = f2bf(v0.w);
  o1.x = f2bf(v1.x); o1.y = f2bf(v1.y); o1.z = f2bf(v1.z); o1.w = f2bf(v1.w);
  unsigned short* dst = qbfF + ((size_t)(((c * 32 + k32) * 4 + mt) * 64 + lane)) * 8;
  *reinterpret_cast<ushort4*>(dst) = o0;
  *reinterpret_cast<ushort4*>(dst + 4) = o1;
}

// ---- prep: imgs -> fragments (rows r>=36 zero) ----
// Layout: ibfF[(((i*32 + k32)*3 + nt)*64 + lane)*8 + j]
//   = imgs[i][r = nt*16 + (lane&15)][k = k32*32 + (lane>>4)*8 + j]
__global__ void k_prep_imgs_frag(const float* __restrict__ imgs,
                                 unsigned short* __restrict__ ibfF) {
  const int k32 = blockIdx.x;
  const int i = blockIdx.y;
  const int t = threadIdx.x;          // 0..191
  const int nt = t >> 6;
  const int lane = t & 63;
  const int r = nt * 16 + (lane & 15);
  const int k0 = k32 * 32 + (lane >> 4) * 8;
  float4 v0 = make_float4(0.f, 0.f, 0.f, 0.f), v1 = v0;
  if (r < NREG) {
    const float* src = imgs + ((size_t)i * NREG + r) * DIM + k0;
    v0 = *reinterpret_cast<const float4*>(src);
    v1 = *reinterpret_cast<const float4*>(src + 4);
  }
  ushort4 o0, o1;
  o0.x = f2bf(v0.x); o0.y = f2bf(v0.y); o0.z = f2bf(v0.z); o0.w = f2bf(v0.w);
  o1.x = f2bf(v1.x); o1.y = f2bf(v1.y); o1.z = f2bf(v1.z); o1.w = f2bf(v1.w);
  unsigned short* dst = ibfF + ((size_t)(((i * 32 + k32) * 3 + nt) * 64 + lane)) * 8;
  *reinterpret_cast<ushort4*>(dst) = o0;
  *reinterpret_cast<ushort4*>(dst + 4) = o1;
}

// ---- Gram via MFMA: one wave per image (same ibfF line feeds both operands) ----
__global__ void k_gram_mfma(const float* __restrict__ imgs,
                            const unsigned short* __restrict__ ibfF,
                            unsigned short* __restrict__ gbf,
                            float* __restrict__ gdiag) {
  const int i = blockIdx.x;
  const int lane = threadIdx.x & 63;
  const int l15 = lane & 15;
  const int quad = lane >> 4;

  // exact fp32 diag: rows r0+quad, k split across the 16 lanes of each quad
  float* dg = gdiag + (size_t)i * 48;
#pragma unroll
  for (int r0 = 0; r0 < 36; r0 += 4) {
    const int r = r0 + quad;
    const float* row = imgs + ((size_t)i * NREG + r) * DIM;
    float ss = 0.f;
#pragma unroll
    for (int p = 0; p < 16; ++p) {
      float4 v = *reinterpret_cast<const float4*>(row + p * 64 + l15 * 4);
      ss += v.x * v.x + v.y * v.y + v.z * v.z + v.w * v.w;
    }
    ss += __shfl_xor(ss, 1); ss += __shfl_xor(ss, 2);
    ss += __shfl_xor(ss, 4); ss += __shfl_xor(ss, 8);
    if (l15 == 0) dg[r] = ss;
  }
  if (lane < 12) dg[36 + lane] = 0.f;

  const unsigned short* base = ibfF + ((size_t)i * 32 * 3) * 512 + lane * 8;
  const f32x4 zero4 = {0.f, 0.f, 0.f, 0.f};
  f32x4 acc[3][3];
#pragma unroll
  for (int na = 0; na < 3; ++na)
#pragma unroll
    for (int nb = 0; nb < 3; ++nb) acc[na][nb] = zero4;
  bf16x8 f[2][3];
#pragma unroll
  for (int nt = 0; nt < 3; ++nt)
    f[0][nt] = *reinterpret_cast<const bf16x8*>(base + (size_t)nt * 512);
#pragma unroll
  for (int k32 = 0; k32 < 32; ++k32) {
    if (k32 + 1 < 32) {
      const int nb_ = (k32 + 1) & 1;
#pragma unroll
      for (int nt = 0; nt < 3; ++nt)
        f[nb_][nt] = *reinterpret_cast<const bf16x8*>(base + ((size_t)(k32 + 1) * 3 + nt) * 512);
    }
    const int b = k32 & 1;
#pragma unroll
    for (int na = 0; na < 3; ++na)
#pragma unroll
      for (int nb = 0; nb < 3; ++nb)
        acc[na][nb] = __builtin_amdgcn_mfma_f32_16x16x32_bf16(f[b][na], f[b][nb], acc[na][nb], 0, 0, 0);
  }
  unsigned short* g = gbf + (size_t)i * (48 * 64);
#pragma unroll
  for (int na = 0; na < 3; ++na)
#pragma unroll
    for (int nb = 0; nb < 3; ++nb)
#pragma unroll
      for (int rg = 0; rg < 4; ++rg) {
        const int r = na * 16 + quad * 4 + rg;   // C row
        const int c = nb * 16 + l15;             // C col
        g[r * 64 + c] = (r == c) ? (unsigned short)0 : f2bf(acc[na][nb][rg]);
      }
  // zero the K-pad cols 48..63 (16 ushorts = 2 uint4 per row)
  for (int idx = lane; idx < 96; idx += 64) {
    const int r = idx >> 1, half = idx & 1;
    *reinterpret_cast<uint4*>(g + r * 64 + 48 + half * 8) = make_uint4(0, 0, 0, 0);
  }
}

// ---- K-loop: S^T = imgs x caps^T, depth-3 register pipeline, SADDR form ----
// aBase/bBase are WAVE-UNIFORM (readfirstlane'd) -> SGPR base; lane8 is the
// only divergent term -> voffset. Per-k32 base advance rides the SALU pipe.
template <int MLIM>
__device__ __forceinline__ void kloopT(const unsigned short* __restrict__ aBase,  // caps, uniform
                                       const unsigned short* __restrict__ bBase,  // imgs, uniform
                                       const int lane8,
                                       f32x4 (&acc)[3][4]) {
  bf16x8 fa[3][MLIM], fb[3][3];
  auto load = [&](int k32, int buf) __attribute__((always_inline)) {
#pragma unroll
    for (int nt = 0; nt < 3; ++nt)
      fb[buf][nt] = *reinterpret_cast<const bf16x8*>(bBase + (size_t)k32 * 1536 + nt * 512 + lane8);
#pragma unroll
    for (int mt = 0; mt < MLIM; ++mt)
      fa[buf][mt] = *reinterpret_cast<const bf16x8*>(aBase + (size_t)k32 * 2048 + mt * 512 + lane8);
  };
  auto compute = [&](int buf) __attribute__((always_inline)) {
#pragma unroll
    for (int mt = 0; mt < MLIM; ++mt)
#pragma unroll
      for (int nt = 0; nt < 3; ++nt)
        acc[nt][mt] = __builtin_amdgcn_mfma_f32_16x16x32_bf16(fb[buf][nt], fa[buf][mt], acc[nt][mt], 0, 0, 0);
  };
  load(0, 0);
  load(1, 1);
#pragma unroll
  for (int k32 = 0; k32 < 32; ++k32) {
    if (k32 + 2 < 32) load(k32 + 2, (k32 + 2) % 3);
    __builtin_amdgcn_sched_barrier(0);   // pin: prefetch issued above, MFMAs stay below
    compute(k32 % 3);
  }
}

// ---- main fused kernel ----
// Grid (I/2, C/2), block 256 = 4 waves: wave wv -> (cap wv&1 of sorted pair,
// img i0+(wv>>1)); wave pairs share A/B fragment lines via L1.
// XCD swizzle: each XCD owns a 16-wide image-pair stripe.
__launch_bounds__(256, 3)
__global__ void k_main(const unsigned short* __restrict__ qbfF,
                       const unsigned short* __restrict__ ibfF,
                       const float* __restrict__ w1sq,
                       const unsigned short* __restrict__ gbf,
                       const float* __restrict__ gdiag,
                       const int* __restrict__ cap_lens,
                       const int* __restrict__ perm,
                       float* __restrict__ out) {
  __shared__ struct {
    unsigned short attn[4][4096];     // bf16 [w][r], r-groups XOR-swizzled by l15&7
    float w12[4][64];
    float w2d[4][64];
    float w2x[4][64];
  } lds;                               // 35840 B
  const int tid = threadIdx.x;
  const int lane = tid & 63;
  const int wv = tid >> 6;
  const int l15 = lane & 15;
  const int quad = lane >> 4;
  // ---- XCD-aware swizzle (16384 blocks, %8==0 -> bijective) ----
  const int flat = blockIdx.y * (NIMG / 2) + blockIdx.x;
  const int xcd = flat & 7;
  const int idx = flat >> 3;
  const int bx = xcd * 16 + (idx & 15);
  const int by = idx >> 4;
  const int i0 = bx * 2;
  const int cA = perm[2 * by], cB = perm[2 * by + 1];
  // c/img are wave-uniform but wv-derived; divergence analysis can't see it.
  // readfirstlane proves uniformity -> all dependent bases go to SGPRs.
  const int c = __builtin_amdgcn_readfirstlane((wv & 1) ? cB : cA);
  const int img = __builtin_amdgcn_readfirstlane(i0 + (wv >> 1));
  const int clen = cap_lens[c];
  const int mlim = __builtin_amdgcn_readfirstlane((clen + 15) >> 4);   // 1..4 valid w-tiles

  f32x4 acc[3][4];
  const f32x4 zero4 = {0.f, 0.f, 0.f, 0.f};
#pragma unroll
  for (int nt = 0; nt < 3; ++nt)
#pragma unroll
    for (int mt = 0; mt < 4; ++mt) acc[nt][mt] = zero4;

  const unsigned short* aBase = qbfF + (size_t)c * (32 * 4 * 512);   // uniform
  const unsigned short* bBase = ibfF + (size_t)img * (32 * 3 * 512); // uniform
  const int lane8 = lane * 8;

  switch (mlim) {
    case 1: kloopT<1>(aBase, bBase, lane8, acc); break;
    case 2: kloopT<2>(aBase, bBase, lane8, acc); break;
    case 3: kloopT<3>(aBase, bBase, lane8, acc); break;
    default: kloopT<4>(aBase, bBase, lane8, acc); break;
  }

  // ---- epilogue (wave-private LDS; in-wave lgkmcnt ordering suffices) ----
  {
    uint4* ab = reinterpret_cast<uint4*>(&lds.attn[wv][0]);
    const uint4 z4 = make_uint4(0, 0, 0, 0);
    for (int j = lane; j < 512; j += 64) ab[j] = z4;   // zero all (incl. pad groups)
  }

  // exact diag per register row r = nt*16 + quad*4 + rg
  const float* dg = gdiag + (size_t)img * 48;          // uniform base
  float dv[3][4];
#pragma unroll
  for (int nt = 0; nt < 3; ++nt)
#pragma unroll
    for (int rg = 0; rg < 4; ++rg)
      dv[nt][rg] = dg[nt * 16 + quad * 4 + rg];

  // pass 1: per-region l2 norm over w -> scale (in-reg over mt, then xor1..8)
  float scale[3][4];
#pragma unroll
  for (int nt = 0; nt < 3; ++nt)
#pragma unroll
    for (int rg = 0; rg < 4; ++rg) {
      float p = 0.f;
#pragma unroll
      for (int mt = 0; mt < 4; ++mt)
        if (mt < mlim) {
          const float s = acc[nt][mt][rg];
          const float l = s < 0.f ? 0.1f * s : s;
          p += l * l;
        }
      p += __shfl_xor(p, 1); p += __shfl_xor(p, 2);
      p += __shfl_xor(p, 4); p += __shfl_xor(p, 8);
      scale[nt][rg] = 9.0f / (sqrtf(p) + 1e-8f);   // SMOOTH folded in
    }

  // pass 2: softmax over r per w-column. |t| <= 9 -> no max subtraction.
  // Invalid r (>=36): nt==2 && quad!=0 -> e=0. Normalized attn packed as bf16
  // pairs in 24 u32 regs (bit-identical to the LDS attn values).
  unsigned a_pk[4][3][2];
#pragma unroll
  for (int mt = 0; mt < 4; ++mt) {
    if (mt >= mlim) continue;
    float ee[3][4];
    float sm = 0.f, wp = 0.f, dd = 0.f;
#pragma unroll
    for (int nt = 0; nt < 3; ++nt) {
      const bool rvalid = (nt < 2) || (quad == 0);
#pragma unroll
      for (int rg = 0; rg < 4; ++rg) {
        const float s = acc[nt][mt][rg];
        const float l = s < 0.f ? 0.1f * s : s;
        const float e0 = rvalid ? __expf(l * scale[nt][rg]) : 0.f;
        ee[nt][rg] = e0;
        sm += e0;
        wp += e0 * s;                       // w12 uses RAW s
        dd += e0 * e0 * dv[nt][rg];         // exact diag term
      }
    }
    sm += __shfl_xor(sm, 16); sm += __shfl_xor(sm, 32);
    wp += __shfl_xor(wp, 16); wp += __shfl_xor(wp, 32);
    dd += __shfl_xor(dd, 16); dd += __shfl_xor(dd, 32);
    const float inv = 1.0f / sm;
    const int w = mt * 16 + l15;
    const int key = l15 & 7;
    unsigned short* arow = &lds.attn[wv][w * 64];
#pragma unroll
    for (int nt = 0; nt < 3; ++nt)
#pragma unroll
      for (int pr = 0; pr < 2; ++pr) {
        const unsigned b0 = f2bf(ee[nt][2 * pr] * inv);
        const unsigned b1 = f2bf(ee[nt][2 * pr + 1] * inv);
        const unsigned pk = b0 | (b1 << 16);
        a_pk[mt][nt][pr] = pk;
        // r0 even, r1 = r0+1: same 8-group, adjacent -> one aligned u32 store
        const int r0 = nt * 16 + quad * 4 + 2 * pr;
        *reinterpret_cast<unsigned*>(&arow[(((r0 >> 3) ^ key) << 3) + (r0 & 7)]) = pk;
      }
    if (quad == 0) { lds.w12[wv][w] = wp * inv; lds.w2d[wv][w] = dd * inv * inv; }
  }

  // Yt = G x Attn^T via MFMA (A=G rows r, B=attn cols w) -> Yt[nt][rg] at lane
  // (l15,quad) = Y[r = nt*16+quad*4+rg][w = mt*16+l15]: SAME layout as a_pk.
  const unsigned short* gBase = gbf + (size_t)img * (48 * 64);   // uniform base
  bf16x8 gfrag[3][2];
#pragma unroll
  for (int nt = 0; nt < 3; ++nt)
#pragma unroll
    for (int ks = 0; ks < 2; ++ks)
      gfrag[nt][ks] = *reinterpret_cast<const bf16x8*>(
          gBase + (nt * 16 + l15) * 64 + ((ks * 4 + quad) << 3));
#pragma unroll
  for (int mt = 0; mt < 4; ++mt) {
    if (mt >= mlim) continue;
    bf16x8 af[2];
#pragma unroll
    for (int ks = 0; ks < 2; ++ks)
      af[ks] = *reinterpret_cast<const bf16x8*>(
          &lds.attn[wv][(mt * 16 + l15) * 64 + (((ks * 4 + quad) ^ (l15 & 7)) << 3)]);
    f32x4 Yt[3] = {zero4, zero4, zero4};
#pragma unroll
    for (int nt = 0; nt < 3; ++nt)
#pragma unroll
      for (int ks = 0; ks < 2; ++ks)
        Yt[nt] = __builtin_amdgcn_mfma_f32_16x16x32_bf16(gfrag[nt][ks], af[ks], Yt[nt], 0, 0, 0);
    // cross term: w2x[w] = sum_r a[w][r] * Y[r][w]; a unpacked from bf16 pairs
    float p = 0.f;
#pragma unroll
    for (int nt = 0; nt < 3; ++nt)
#pragma unroll
      for (int pr = 0; pr < 2; ++pr) {
        const unsigned pk = a_pk[mt][nt][pr];
        const float a0 = __uint_as_float(pk << 16);
        const float a1 = __uint_as_float(pk & 0xffff0000u);
        p += a0 * Yt[nt][2 * pr] + a1 * Yt[nt][2 * pr + 1];
      }
    p += __shfl_xor(p, 16); p += __shfl_xor(p, 32);
    if (quad == 0) lds.w2x[wv][mt * 16 + l15] = p;
  }

  // final: lane = word
  const float* w1Base = w1sq + (size_t)c * WPAD;   // uniform base
  float simv = 0.f;
  if (lane < clen) {
    const float w2sq = fmaxf(lds.w2x[wv][lane] + lds.w2d[wv][lane], 0.f);
    const float w2v = sqrtf(w2sq);
    const float w12v = lds.w12[wv][lane];
    const float w1v = sqrtf(w1Base[lane]);
    simv = w12v / fmaxf(w1v * w2v, 1e-8f);
  }
  simv += __shfl_xor(simv, 1);
  simv += __shfl_xor(simv, 2);
  simv += __shfl_xor(simv, 4);
  simv += __shfl_xor(simv, 8);
  simv += __shfl_xor(simv, 16);
  simv += __shfl_xor(simv, 32);
  if (lane == 0) out[(size_t)img * NCAP + c] = simv / (float)clen;
}

extern "C" void kernel_launch(void* const* d_in, const int* in_sizes, int n_in,
                              void* d_out, int out_size, void* d_ws, size_t ws_size,
                              hipStream_t stream) {
  const float* imgs = (const float*)d_in[0];
  const float* caps = (const float*)d_in[1];
  const int* cap_lens = (const int*)d_in[3];   // img_lens (d_in[2]) unused by reference
  float* out = (float*)d_out;

  char* ws = (char*)d_ws;
  const size_t QBF_B = (size_t)NCAP * 32 * 4 * 512 * 2;      // 33,554,432
  const size_t IBF_B = (size_t)NIMG * 32 * 3 * 512 * 2;      // 25,165,824
  const size_t W1_B = (size_t)NCAP * WPAD * 4;               // 65,536
  const size_t GBF_B = (size_t)NIMG * 48 * 64 * 2;           // 1,572,864
  const size_t GD_B = (size_t)NIMG * 48 * 4;                 // 49,152
  unsigned short* qbfF = (unsigned short*)ws;
  unsigned short* ibfF = (unsigned short*)(ws + QBF_B);
  float* w1sq = (float*)(ws + QBF_B + IBF_B);
  unsigned short* gbf = (unsigned short*)(ws + QBF_B + IBF_B + W1_B);
  float* gdiag = (float*)(ws + QBF_B + IBF_B + W1_B + GBF_B);
  int* perm = (int*)(ws + QBF_B + IBF_B + W1_B + GBF_B + GD_B);

  k_sort<<<1, NCAP, 0, stream>>>(cap_lens, perm, w1sq);
  k_prep_caps_frag<<<dim3(32, NCAP), 256, 0, stream>>>(caps, cap_lens, qbfF, w1sq);
  k_prep_imgs_frag<<<dim3(32, NIMG), 192, 0, stream>>>(imgs, ibfF);
  k_gram_mfma<<<NIMG, 64, 0, stream>>>(imgs, ibfF, gbf, gdiag);
  k_main<<<dim3(NIMG / 2, NCAP / 2), 256, 0, stream>>>(qbfF, ibfF, w1sq, gbf, gdiag, cap_lens, perm, out);
}

// Round 11
// 513.078 us; speedup vs baseline: 1.2929x; 1.0336x over previous
//
#include <hip/hip_runtime.h>

// T2ICrossAttentionPool on MI355X.
// Identities: w12[c,i,w] = sum_r attn*Sraw;  |wctx|^2 = a^T G a with
//   G = exact fp32 diag (register math) + off-diag G' bf16 (MFMA quadratic form).
// R13/R19: transposed epilogue, depth-3 reg K-loop, (256,3): ~433us k_main.
// R14-R18 (staging arc, CLOSED): LDS staging loses (barrier lock-step).
// R20: readfirstlane saddr: neutral -> K-loop is TA-BANDWIDTH-bound.
//   Arithmetic: 12.4GB fragment bytes / 39TB/s TA ceiling = 295us K-loop floor.
// R21: fat waves: 1 cap x 2 img per wave. A-fragments reused across 2 images:
//   loads/k32 (mlim+3)->(mlim+6) for 2x output -> TA bytes -25% (floor 244us).
//   acc[2][3][4]=96 regs -> launch_bounds(256,2), depth-2 pipeline (~180 regs).
//   Bandwidth-bound => occupancy 2/SIMD suffices (72KB in flight >> 13KB need).
//   Epilogue sequential per image, attn LDS slice reused (pad groups stay 0).

#define NIMG 256
#define NREG 36
#define DIM 1024
#define NCAP 256
#define MAXW 60
#define WPAD 64

typedef short bf16x8 __attribute__((ext_vector_type(8)));
typedef float f32x4 __attribute__((ext_vector_type(4)));

__device__ __forceinline__ unsigned short f2bf(float f) {
  unsigned u = __float_as_uint(f);
  u += 0x7FFF + ((u >> 16) & 1);   // round-to-nearest-even
  return (unsigned short)(u >> 16);
}

// ---- prep: caption permutation sorted by length (rank-count) + zero w1sq ----
// Zeroing here makes the caps_frag atomicAdd accumulation replay-idempotent.
__global__ void k_sort(const int* __restrict__ cap_lens, int* __restrict__ perm,
                       float* __restrict__ w1sq) {
  const int i = threadIdx.x;           // 256 threads
#pragma unroll
  for (int j = 0; j < WPAD; ++j) w1sq[i * WPAD + j] = 0.f;
  const int li = cap_lens[i];
  int r = 0;
  for (int j = 0; j < NCAP; ++j) {
    const int lj = cap_lens[j];
    r += (lj < li) || (lj == li && j < i);
  }
  perm[r] = i;
}

// ---- prep: caps -> fragments, masked (rows w>=clen zero); fused w1 partial ----
// Layout: qbfF[(((c*32 + k32)*4 + mt)*64 + lane)*8 + j]
//   = q[c][m = mt*16 + (lane&15)][k = k32*32 + (lane>>4)*8 + j]
// w1sq[c][m] += sum_k(q^2) over this block's 32-k slice (fp32, pre-bf16).
__global__ void k_prep_caps_frag(const float* __restrict__ caps, const int* __restrict__ cap_lens,
                                 unsigned short* __restrict__ qbfF,
                                 float* __restrict__ w1sq) {
  const int k32 = blockIdx.x;
  const int c = blockIdx.y;
  const int t = threadIdx.x;
  const int mt = t >> 6;
  const int lane = t & 63;
  const int m = mt * 16 + (lane & 15);
  const int k0 = k32 * 32 + (lane >> 4) * 8;
  const int clen = cap_lens[c];
  float4 v0 = make_float4(0.f, 0.f, 0.f, 0.f), v1 = v0;
  if (m < clen && m < MAXW) {
    const float* src = caps + ((size_t)c * MAXW + m) * DIM + k0;
    v0 = *reinterpret_cast<const float4*>(src);
    v1 = *reinterpret_cast<const float4*>(src + 4);
  }
  float ss = v0.x * v0.x + v0.y * v0.y + v0.z * v0.z + v0.w * v0.w
           + v1.x * v1.x + v1.y * v1.y + v1.z * v1.z + v1.w * v1.w;
  ss += __shfl_xor(ss, 16);
  ss += __shfl_xor(ss, 32);
  if ((lane >> 4) == 0 && ss != 0.f) atomicAdd(&w1sq[(size_t)c * WPAD + m], ss);
  ushort4 o0, o1;
  o0.x = f2bf(v0.x); o0.y = f2bf(v0.y); o0.z = f2bf(v0.z); o0.w = f2bf(v0.w);
  o1.x = f2bf(v1.x); o1.y = f2bf(v1.y); o1.z = f2bf(v1.z); o1.w = f2bf(v1.w);
  unsigned short* dst = qbfF + ((size_t)(((c * 32 + k32) * 4 + mt) * 64 + lane)) * 8;
  *reinterpret_cast<ushort4*>(dst) = o0;
  *reinterpret_cast<ushort4*>(dst + 4) = o1;
}

// ---- prep: imgs -> fragments (rows r>=36 zero) ----
// Layout: ibfF[(((i*32 + k32)*3 + nt)*64 + lane)*8 + j]
//   = imgs[i][r = nt*16 + (lane&15)][k = k32*32 + (lane>>4)*8 + j]
__global__ void k_prep_imgs_frag(const float* __restrict__ imgs,
                                 unsigned short* __restrict__ ibfF) {
  const int k32 = blockIdx.x;
  const int i = blockIdx.y;
  const int t = threadIdx.x;          // 0..191
  const int nt = t >> 6;
  const int lane = t & 63;
  const int r = nt * 16 + (lane & 15);
  const int k0 = k32 * 32 + (lane >> 4) * 8;
  float4 v0 = make_float4(0.f, 0.f, 0.f, 0.f), v1 = v0;
  if (r < NREG) {
    const float* src = imgs + ((size_t)i * NREG + r) * DIM + k0;
    v0 = *reinterpret_cast<const float4*>(src);
    v1 = *reinterpret_cast<const float4*>(src + 4);
  }
  ushort4 o0, o1;
  o0.x = f2bf(v0.x); o0.y = f2bf(v0.y); o0.z = f2bf(v0.z); o0.w = f2bf(v0.w);
  o1.x = f2bf(v1.x); o1.y = f2bf(v1.y); o1.z = f2bf(v1.z); o1.w = f2bf(v1.w);
  unsigned short* dst = ibfF + ((size_t)(((i * 32 + k32) * 3 + nt) * 64 + lane)) * 8;
  *reinterpret_cast<ushort4*>(dst) = o0;
  *reinterpret_cast<ushort4*>(dst + 4) = o1;
}

// ---- Gram via MFMA: one wave per image (same ibfF line feeds both operands) ----
__global__ void k_gram_mfma(const float* __restrict__ imgs,
                            const unsigned short* __restrict__ ibfF,
                            unsigned short* __restrict__ gbf,
                            float* __restrict__ gdiag) {
  const int i = blockIdx.x;
  const int lane = threadIdx.x & 63;
  const int l15 = lane & 15;
  const int quad = lane >> 4;

  // exact fp32 diag: rows r0+quad, k split across the 16 lanes of each quad
  float* dg = gdiag + (size_t)i * 48;
#pragma unroll
  for (int r0 = 0; r0 < 36; r0 += 4) {
    const int r = r0 + quad;
    const float* row = imgs + ((size_t)i * NREG + r) * DIM;
    float ss = 0.f;
#pragma unroll
    for (int p = 0; p < 16; ++p) {
      float4 v = *reinterpret_cast<const float4*>(row + p * 64 + l15 * 4);
      ss += v.x * v.x + v.y * v.y + v.z * v.z + v.w * v.w;
    }
    ss += __shfl_xor(ss, 1); ss += __shfl_xor(ss, 2);
    ss += __shfl_xor(ss, 4); ss += __shfl_xor(ss, 8);
    if (l15 == 0) dg[r] = ss;
  }
  if (lane < 12) dg[36 + lane] = 0.f;

  const unsigned short* base = ibfF + ((size_t)i * 32 * 3) * 512 + lane * 8;
  const f32x4 zero4 = {0.f, 0.f, 0.f, 0.f};
  f32x4 acc[3][3];
#pragma unroll
  for (int na = 0; na < 3; ++na)
#pragma unroll
    for (int nb = 0; nb < 3; ++nb) acc[na][nb] = zero4;
  bf16x8 f[2][3];
#pragma unroll
  for (int nt = 0; nt < 3; ++nt)
    f[0][nt] = *reinterpret_cast<const bf16x8*>(base + (size_t)nt * 512);
#pragma unroll
  for (int k32 = 0; k32 < 32; ++k32) {
    if (k32 + 1 < 32) {
      const int nb_ = (k32 + 1) & 1;
#pragma unroll
      for (int nt = 0; nt < 3; ++nt)
        f[nb_][nt] = *reinterpret_cast<const bf16x8*>(base + ((size_t)(k32 + 1) * 3 + nt) * 512);
    }
    const int b = k32 & 1;
#pragma unroll
    for (int na = 0; na < 3; ++na)
#pragma unroll
      for (int nb = 0; nb < 3; ++nb)
        acc[na][nb] = __builtin_amdgcn_mfma_f32_16x16x32_bf16(f[b][na], f[b][nb], acc[na][nb], 0, 0, 0);
  }
  unsigned short* g = gbf + (size_t)i * (48 * 64);
#pragma unroll
  for (int na = 0; na < 3; ++na)
#pragma unroll
    for (int nb = 0; nb < 3; ++nb)
#pragma unroll
      for (int rg = 0; rg < 4; ++rg) {
        const int r = na * 16 + quad * 4 + rg;   // C row
        const int c = nb * 16 + l15;             // C col
        g[r * 64 + c] = (r == c) ? (unsigned short)0 : f2bf(acc[na][nb][rg]);
      }
  // zero the K-pad cols 48..63 (16 ushorts = 2 uint4 per row)
  for (int idx = lane; idx < 96; idx += 64) {
    const int r = idx >> 1, half = idx & 1;
    *reinterpret_cast<uint4*>(g + r * 64 + 48 + half * 8) = make_uint4(0, 0, 0, 0);
  }
}

// ---- K-loop: 1 cap x 2 img fat wave, depth-2 register pipeline ----
// A (cap) fragments loaded ONCE, feed MFMAs for BOTH images: loads/k32 =
// MLIM+6 for 6*MLIM MFMAs (ratio 1.97 vs 1.48). acc[im][nt][mt].
template <int MLIM>
__device__ __forceinline__ void kloopT2(const unsigned short* __restrict__ aBase,  // cap, uniform
                                        const unsigned short* __restrict__ bBase,  // img0, uniform
                                        const int lane8,
                                        f32x4 (&acc)[2][3][4]) {
  bf16x8 fa[2][MLIM], fb[2][2][3];
  auto load = [&](int k32, int buf) __attribute__((always_inline)) {
#pragma unroll
    for (int im = 0; im < 2; ++im)
#pragma unroll
      for (int nt = 0; nt < 3; ++nt)
        fb[buf][im][nt] = *reinterpret_cast<const bf16x8*>(
            bBase + (size_t)im * (32 * 3 * 512) + (size_t)k32 * 1536 + nt * 512 + lane8);
#pragma unroll
    for (int mt = 0; mt < MLIM; ++mt)
      fa[buf][mt] = *reinterpret_cast<const bf16x8*>(aBase + (size_t)k32 * 2048 + mt * 512 + lane8);
  };
  auto compute = [&](int buf) __attribute__((always_inline)) {
#pragma unroll
    for (int im = 0; im < 2; ++im)
#pragma unroll
      for (int mt = 0; mt < MLIM; ++mt)
#pragma unroll
        for (int nt = 0; nt < 3; ++nt)
          acc[im][nt][mt] = __builtin_amdgcn_mfma_f32_16x16x32_bf16(
              fb[buf][im][nt], fa[buf][mt], acc[im][nt][mt], 0, 0, 0);
  };
  load(0, 0);
#pragma unroll
  for (int k32 = 0; k32 < 32; ++k32) {
    if (k32 + 1 < 32) load(k32 + 1, (k32 + 1) & 1);
    __builtin_amdgcn_sched_barrier(0);   // pin: prefetch issued above, MFMAs stay below
    compute(k32 & 1);
  }
}

// ---- main fused kernel ----
// Grid (I/4, C/2), block 256 = 4 waves: wave wv -> (cap wv&1 of sorted pair,
// imgs i0+2*(wv>>1) .. +1). XCD swizzle: each XCD owns an 8-wide bx stripe
// (32 imgs, 3MB ibfF resident in its L2).
__launch_bounds__(256, 2)
__global__ void k_main(const unsigned short* __restrict__ qbfF,
                       const unsigned short* __restrict__ ibfF,
                       const float* __restrict__ w1sq,
                       const unsigned short* __restrict__ gbf,
                       const float* __restrict__ gdiag,
                       const int* __restrict__ cap_lens,
                       const int* __restrict__ perm,
                       float* __restrict__ out) {
  __shared__ struct {
    unsigned short attn[4][4096];     // bf16 [w][r], r-groups XOR-swizzled; reused per image
    float w12[4][64];
    float w2d[4][64];
    float w2x[4][64];
  } lds;                               // 35840 B -> 2 blocks/CU at (256,2)
  const int tid = threadIdx.x;
  const int lane = tid & 63;
  const int wv = tid >> 6;
  const int l15 = lane & 15;
  const int quad = lane >> 4;
  // ---- XCD-aware swizzle (8192 blocks, %8==0 -> bijective) ----
  const int flat = blockIdx.y * (NIMG / 4) + blockIdx.x;
  const int xcd = flat & 7;
  const int idx = flat >> 3;
  const int bx = xcd * 8 + (idx & 7);
  const int by = idx >> 3;
  const int i0 = bx * 4;
  const int cA = perm[2 * by], cB = perm[2 * by + 1];
  // wave-uniform (readfirstlane proves it to divergence analysis)
  const int c = __builtin_amdgcn_readfirstlane((wv & 1) ? cB : cA);
  const int imgBase = __builtin_amdgcn_readfirstlane(i0 + (wv >> 1) * 2);
  const int clen = cap_lens[c];
  const int mlim = __builtin_amdgcn_readfirstlane((clen + 15) >> 4);   // 1..4 valid w-tiles

  f32x4 acc[2][3][4];
  const f32x4 zero4 = {0.f, 0.f, 0.f, 0.f};
#pragma unroll
  for (int im = 0; im < 2; ++im)
#pragma unroll
    for (int nt = 0; nt < 3; ++nt)
#pragma unroll
      for (int mt = 0; mt < 4; ++mt) acc[im][nt][mt] = zero4;

  const unsigned short* aBase = qbfF + (size_t)c * (32 * 4 * 512);        // uniform
  const unsigned short* bBase = ibfF + (size_t)imgBase * (32 * 3 * 512);  // uniform
  const int lane8 = lane * 8;

  switch (mlim) {
    case 1: kloopT2<1>(aBase, bBase, lane8, acc); break;
    case 2: kloopT2<2>(aBase, bBase, lane8, acc); break;
    case 3: kloopT2<3>(aBase, bBase, lane8, acc); break;
    default: kloopT2<4>(aBase, bBase, lane8, acc); break;
  }

  // ---- epilogue (wave-private LDS; in-wave DS ordering suffices) ----
  // zero attn once; pass2 only ever writes groups {0..5}^key per row, so pad
  // groups stay 0 across both images; rows >= mlim*16 are never read.
  {
    uint4* ab = reinterpret_cast<uint4*>(&lds.attn[wv][0]);
    const uint4 z4 = make_uint4(0, 0, 0, 0);
    for (int j = lane; j < 512; j += 64) ab[j] = z4;
  }
  const float* w1Base = w1sq + (size_t)c * WPAD;   // uniform

#pragma unroll
  for (int im = 0; im < 2; ++im) {
    const int img = imgBase + im;
    // exact diag per register row r = nt*16 + quad*4 + rg
    const float* dg = gdiag + (size_t)img * 48;    // uniform base
    float dv[3][4];
#pragma unroll
    for (int nt = 0; nt < 3; ++nt)
#pragma unroll
      for (int rg = 0; rg < 4; ++rg)
        dv[nt][rg] = dg[nt * 16 + quad * 4 + rg];

    // pass 1: per-region l2 norm over w -> scale (in-reg over mt, then xor1..8)
    float scale[3][4];
#pragma unroll
    for (int nt = 0; nt < 3; ++nt)
#pragma unroll
      for (int rg = 0; rg < 4; ++rg) {
        float p = 0.f;
#pragma unroll
        for (int mt = 0; mt < 4; ++mt)
          if (mt < mlim) {
            const float s = acc[im][nt][mt][rg];
            const float l = s < 0.f ? 0.1f * s : s;
            p += l * l;
          }
        p += __shfl_xor(p, 1); p += __shfl_xor(p, 2);
        p += __shfl_xor(p, 4); p += __shfl_xor(p, 8);
        scale[nt][rg] = 9.0f / (sqrtf(p) + 1e-8f);   // SMOOTH folded in
      }

    // pass 2: softmax over r per w-column. |t| <= 9 -> no max subtraction.
    // Invalid r (>=36): nt==2 && quad!=0 -> e=0. Normalized attn packed as
    // bf16 pairs in 24 u32 regs (bit-identical to the LDS attn values).
    unsigned a_pk[4][3][2];
#pragma unroll
    for (int mt = 0; mt < 4; ++mt) {
      if (mt >= mlim) continue;
      float ee[3][4];
      float sm = 0.f, wp = 0.f, dd = 0.f;
#pragma unroll
      for (int nt = 0; nt < 3; ++nt) {
        const bool rvalid = (nt < 2) || (quad == 0);
#pragma unroll
        for (int rg = 0; rg < 4; ++rg) {
          const float s = acc[im][nt][mt][rg];
          const float l = s < 0.f ? 0.1f * s : s;
          const float e0 = rvalid ? __expf(l * scale[nt][rg]) : 0.f;
          ee[nt][rg] = e0;
          sm += e0;
          wp += e0 * s;                       // w12 uses RAW s
          dd += e0 * e0 * dv[nt][rg];         // exact diag term
        }
      }
      sm += __shfl_xor(sm, 16); sm += __shfl_xor(sm, 32);
      wp += __shfl_xor(wp, 16); wp += __shfl_xor(wp, 32);
      dd += __shfl_xor(dd, 16); dd += __shfl_xor(dd, 32);
      const float inv = 1.0f / sm;
      const int w = mt * 16 + l15;
      const int key = l15 & 7;
      unsigned short* arow = &lds.attn[wv][w * 64];
#pragma unroll
      for (int nt = 0; nt < 3; ++nt)
#pragma unroll
        for (int pr = 0; pr < 2; ++pr) {
          const unsigned b0 = f2bf(ee[nt][2 * pr] * inv);
          const unsigned b1 = f2bf(ee[nt][2 * pr + 1] * inv);
          const unsigned pk = b0 | (b1 << 16);
          a_pk[mt][nt][pr] = pk;
          // r0 even, r1 = r0+1: same 8-group, adjacent -> one aligned u32 store
          const int r0 = nt * 16 + quad * 4 + 2 * pr;
          *reinterpret_cast<unsigned*>(&arow[(((r0 >> 3) ^ key) << 3) + (r0 & 7)]) = pk;
        }
      if (quad == 0) { lds.w12[wv][w] = wp * inv; lds.w2d[wv][w] = dd * inv * inv; }
    }

    // Yt = G x Attn^T via MFMA -> Yt[nt][rg] in the a_pk register layout.
    const unsigned short* gBase = gbf + (size_t)img * (48 * 64);   // uniform
    bf16x8 gfrag[3][2];
#pragma unroll
    for (int nt = 0; nt < 3; ++nt)
#pragma unroll
      for (int ks = 0; ks < 2; ++ks)
        gfrag[nt][ks] = *reinterpret_cast<const bf16x8*>(
            gBase + (nt * 16 + l15) * 64 + ((ks * 4 + quad) << 3));
#pragma unroll
    for (int mt = 0; mt < 4; ++mt) {
      if (mt >= mlim) continue;
      bf16x8 af[2];
#pragma unroll
      for (int ks = 0; ks < 2; ++ks)
        af[ks] = *reinterpret_cast<const bf16x8*>(
            &lds.attn[wv][(mt * 16 + l15) * 64 + (((ks * 4 + quad) ^ (l15 & 7)) << 3)]);
      f32x4 Yt[3] = {zero4, zero4, zero4};
#pragma unroll
      for (int nt = 0; nt < 3; ++nt)
#pragma unroll
        for (int ks = 0; ks < 2; ++ks)
          Yt[nt] = __builtin_amdgcn_mfma_f32_16x16x32_bf16(gfrag[nt][ks], af[ks], Yt[nt], 0, 0, 0);
      // cross term: w2x[w] = sum_r a[w][r] * Y[r][w]; a unpacked from bf16 pairs
      float p = 0.f;
#pragma unroll
      for (int nt = 0; nt < 3; ++nt)
#pragma unroll
        for (int pr = 0; pr < 2; ++pr) {
          const unsigned pk = a_pk[mt][nt][pr];
          const float a0 = __uint_as_float(pk << 16);
          const float a1 = __uint_as_float(pk & 0xffff0000u);
          p += a0 * Yt[nt][2 * pr] + a1 * Yt[nt][2 * pr + 1];
        }
      p += __shfl_xor(p, 16); p += __shfl_xor(p, 32);
      if (quad == 0) lds.w2x[wv][mt * 16 + l15] = p;
    }

    // final: lane = word
    float simv = 0.f;
    if (lane < clen) {
      const float w2sq = fmaxf(lds.w2x[wv][lane] + lds.w2d[wv][lane], 0.f);
      const float w2v = sqrtf(w2sq);
      const float w12v = lds.w12[wv][lane];
      const float w1v = sqrtf(w1Base[lane]);
      simv = w12v / fmaxf(w1v * w2v, 1e-8f);
    }
    simv += __shfl_xor(simv, 1);
    simv += __shfl_xor(simv, 2);
    simv += __shfl_xor(simv, 4);
    simv += __shfl_xor(simv, 8);
    simv += __shfl_xor(simv, 16);
    simv += __shfl_xor(simv, 32);
    if (lane == 0) out[(size_t)img * NCAP + c] = simv / (float)clen;
  }
}

extern "C" void kernel_launch(void* const* d_in, const int* in_sizes, int n_in,
                              void* d_out, int out_size, void* d_ws, size_t ws_size,
                              hipStream_t stream) {
  const float* imgs = (const float*)d_in[0];
  const float* caps = (const float*)d_in[1];
  const int* cap_lens = (const int*)d_in[3];   // img_lens (d_in[2]) unused by reference
  float* out = (float*)d_out;

  char* ws = (char*)d_ws;
  const size_t QBF_B = (size_t)NCAP * 32 * 4 * 512 * 2;      // 33,554,432
  const size_t IBF_B = (size_t)NIMG * 32 * 3 * 512 * 2;      // 25,165,824
  const size_t W1_B = (size_t)NCAP * WPAD * 4;               // 65,536
  const size_t GBF_B = (size_t)NIMG * 48 * 64 * 2;           // 1,572,864
  const size_t GD_B = (size_t)NIMG * 48 * 4;                 // 49,152
  unsigned short* qbfF = (unsigned short*)ws;
  unsigned short* ibfF = (unsigned short*)(ws + QBF_B);
  float* w1sq = (float*)(ws + QBF_B + IBF_B);
  unsigned short* gbf = (unsigned short*)(ws + QBF_B + IBF_B + W1_B);
  float* gdiag = (float*)(ws + QBF_B + IBF_B + W1_B + GBF_B);
  int* perm = (int*)(ws + QBF_B + IBF_B + W1_B + GBF_B + GD_B);

  k_sort<<<1, NCAP, 0, stream>>>(cap_lens, perm, w1sq);
  k_prep_caps_frag<<<dim3(32, NCAP), 256, 0, stream>>>(caps, cap_lens, qbfF, w1sq);
  k_prep_imgs_frag<<<dim3(32, NIMG), 192, 0, stream>>>(imgs, ibfF);
  k_gram_mfma<<<NIMG, 64, 0, stream>>>(imgs, ibfF, gbf, gdiag);
  k_main<<<dim3(NIMG / 4, NCAP / 2), 256, 0, stream>>>(qbfF, ibfF, w1sq, gbf, gdiag, cap_lens, perm, out);
}